// Round 2
// baseline (20074.606 us; speedup 1.0000x reference)
//
#include <hip/hip_runtime.h>
#include <hip/hip_bf16.h>

// Problem constants (B=2, S=1024, E=1024, H=16, D=64)
#define S_LEN 1024
#define E_DIM 1024
#define NH 16
#define HD 64
#define M_ROWS 2048   // B*S
#define BH_CNT 32     // B*NH

static constexpr float LR_C = 0.01f;
static constexpr float SC_C = 0.125f;  // 1/sqrt(64)

// ---------------- elementwise ----------------
__global__ void k_sub(const float* __restrict__ a, const float* __restrict__ b,
                      float* __restrict__ o, int n) {
  int i = blockIdx.x * 256 + threadIdx.x;
  if (i < n) o[i] = a[i] - b[i];
}

// Dv[(b*H+h)*S + s] = dot(g_row_head, o_row_head) over 64 dims. One 64-thread block per row-head.
__global__ void k_rowdot(const float* __restrict__ g, const float* __restrict__ o,
                         float* __restrict__ Dv) {
  int r = blockIdx.x / NH;   // flat row in [0, 2048)
  int h = blockIdx.x % NH;
  int d = threadIdx.x;
  size_t idx = (size_t)r * E_DIM + h * HD + d;
  float v = g[idx] * o[idx];
  for (int off = 32; off; off >>= 1) v += __shfl_xor(v, off, 64);
  if (d == 0) {
    int b = r / S_LEN, s = r % S_LEN;
    Dv[(size_t)(b * NH + h) * S_LEN + s] = v;
  }
}

// ---------------- fp32 tiled GEMM: C[M,N] op= A[M,K] * op(B) ----------------
// TRANSB=1: op(B)[k][n] = Bm[n*K+k]  (x @ W^T style, W is [N,K] row-major)
// TRANSB=0: op(B)[k][n] = Bm[k*N+n]  (plain A @ B)
// MODE 0: C = acc;  MODE 1: C = T - acc;  MODE 2: C += alpha*acc
// M=2048, N=K=1024. grid = (N/128, M/128), block = 256.
template <int TRANSB, int MODE>
__global__ __launch_bounds__(256) void gemm128(const float* __restrict__ A,
                                               const float* __restrict__ Bm,
                                               float* __restrict__ C,
                                               const float* __restrict__ T, float alpha) {
  const int K = 1024, N = 1024;
  __shared__ float As[16][128];
  __shared__ float Bs[16][128];
  int tid = threadIdx.x;
  int m0 = blockIdx.y * 128, n0 = blockIdx.x * 128;
  int tx = tid % 16, ty = tid / 16;
  float acc[8][8] = {};

  for (int k0 = 0; k0 < K; k0 += 16) {
    #pragma unroll
    for (int t = 0; t < 2; t++) {
      int idx = tid * 2 + t;
      int r = idx >> 2, kp = (idx & 3) * 4;
      float4 av = *(const float4*)(A + (size_t)(m0 + r) * K + k0 + kp);
      As[kp + 0][r] = av.x; As[kp + 1][r] = av.y;
      As[kp + 2][r] = av.z; As[kp + 3][r] = av.w;
    }
    if (TRANSB) {
      #pragma unroll
      for (int t = 0; t < 2; t++) {
        int idx = tid * 2 + t;
        int r = idx >> 2, kp = (idx & 3) * 4;
        float4 bv = *(const float4*)(Bm + (size_t)(n0 + r) * K + k0 + kp);
        Bs[kp + 0][r] = bv.x; Bs[kp + 1][r] = bv.y;
        Bs[kp + 2][r] = bv.z; Bs[kp + 3][r] = bv.w;
      }
    } else {
      #pragma unroll
      for (int t = 0; t < 2; t++) {
        int idx = tid * 2 + t;
        int kk = idx >> 5, c = (idx & 31) * 4;
        *(float4*)&Bs[kk][c] = *(const float4*)(Bm + (size_t)(k0 + kk) * N + n0 + c);
      }
    }
    __syncthreads();
    #pragma unroll
    for (int kk = 0; kk < 16; kk++) {
      float a[8], b[8];
      *(float4*)&a[0] = *(float4*)&As[kk][ty * 8];
      *(float4*)&a[4] = *(float4*)&As[kk][ty * 8 + 4];
      *(float4*)&b[0] = *(float4*)&Bs[kk][tx * 8];
      *(float4*)&b[4] = *(float4*)&Bs[kk][tx * 8 + 4];
      #pragma unroll
      for (int ii = 0; ii < 8; ii++)
        #pragma unroll
        for (int jj = 0; jj < 8; jj++) acc[ii][jj] += a[ii] * b[jj];
    }
    __syncthreads();
  }

  #pragma unroll
  for (int ii = 0; ii < 8; ii++) {
    size_t crow = (size_t)(m0 + ty * 8 + ii) * N + n0 + tx * 8;
    if (MODE == 0) {
      #pragma unroll
      for (int jj = 0; jj < 8; jj++) C[crow + jj] = acc[ii][jj];
    } else if (MODE == 1) {
      #pragma unroll
      for (int jj = 0; jj < 8; jj++) C[crow + jj] = T[crow + jj] - acc[ii][jj];
    } else {
      #pragma unroll
      for (int jj = 0; jj < 8; jj++) C[crow + jj] += alpha * acc[ii][jj];
    }
  }
}

// ---------------- attention forward (one block per (head, query-row)) ----------------
// grid (S, BH), block (64, 8). Saves m and 1/l per row for the backward recompute.
__global__ __launch_bounds__(512) void attn_fwd(const float* __restrict__ Q,
                                                const float* __restrict__ K,
                                                const float* __restrict__ V,
                                                float* __restrict__ O,
                                                float* __restrict__ mbuf,
                                                float* __restrict__ lbuf) {
  int i = blockIdx.x, bh = blockIdx.y;
  int b = bh / NH, h = bh % NH;
  int d = threadIdx.x, y = threadIdx.y;
  int tid = d + 64 * y;
  __shared__ float sc[S_LEN];
  __shared__ float red[16];
  __shared__ float oacc[8][64];

  size_t rowi = (size_t)(b * S_LEN + i) * E_DIM + h * HD;
  float qd = Q[rowi + d];
  int nj = i + 1;

  for (int j = y; j < nj; j += 8) {
    float p = qd * K[(size_t)(b * S_LEN + j) * E_DIM + h * HD + d];
    for (int off = 32; off; off >>= 1) p += __shfl_xor(p, off, 64);
    if (d == 0) sc[j] = p * SC_C;
  }
  __syncthreads();

  float mx = -1e30f;
  for (int j = tid; j < nj; j += 512) mx = fmaxf(mx, sc[j]);
  for (int off = 32; off; off >>= 1) mx = fmaxf(mx, __shfl_xor(mx, off, 64));
  if (d == 0) red[y] = mx;
  __syncthreads();
  if (tid == 0) {
    float m = red[0];
    for (int w = 1; w < 8; w++) m = fmaxf(m, red[w]);
    red[8] = m;
  }
  __syncthreads();
  float m = red[8];

  float se = 0.f;
  for (int j = tid; j < nj; j += 512) {
    float e = __expf(sc[j] - m);
    sc[j] = e;
    se += e;
  }
  for (int off = 32; off; off >>= 1) se += __shfl_xor(se, off, 64);
  if (d == 0) red[y] = se;
  __syncthreads();
  if (tid == 0) {
    float s = 0.f;
    for (int w = 0; w < 8; w++) s += red[w];
    red[9] = s;
  }
  __syncthreads();
  float linv = 1.0f / red[9];

  float acc = 0.f;
  for (int j = y; j < nj; j += 8)
    acc += sc[j] * V[(size_t)(b * S_LEN + j) * E_DIM + h * HD + d];
  oacc[y][d] = acc;
  __syncthreads();
  if (y == 0) {
    float s = 0.f;
    for (int w = 0; w < 8; w++) s += oacc[w][d];
    O[rowi + d] = s * linv;
    if (d == 0) {
      mbuf[(size_t)(b * NH + h) * S_LEN + i] = m;
      lbuf[(size_t)(b * NH + h) * S_LEN + i] = linv;
    }
  }
}

// ---------------- attention backward: dq (row-parallel) ----------------
__global__ __launch_bounds__(512) void attn_bwd_q(const float* __restrict__ Q,
                                                  const float* __restrict__ K,
                                                  const float* __restrict__ V,
                                                  const float* __restrict__ G,
                                                  const float* __restrict__ mbuf,
                                                  const float* __restrict__ lbuf,
                                                  const float* __restrict__ Dv,
                                                  float* __restrict__ GQ) {
  int i = blockIdx.x, bh = blockIdx.y;
  int b = bh / NH, h = bh % NH;
  int d = threadIdx.x, y = threadIdx.y;
  size_t rowi = (size_t)(b * S_LEN + i) * E_DIM + h * HD;
  size_t sid = (size_t)(b * NH + h) * S_LEN + i;
  float qd = Q[rowi + d], gd = G[rowi + d];
  float mi = mbuf[sid], linv = lbuf[sid], Di = Dv[sid];
  float gq = 0.f;
  for (int j = y; j <= i; j += 8) {
    size_t rowj = (size_t)(b * S_LEN + j) * E_DIM + h * HD;
    float kd = K[rowj + d];
    float vd = V[rowj + d];
    float s = qd * kd, gdot = gd * vd;
    for (int off = 32; off; off >>= 1) {
      s += __shfl_xor(s, off, 64);
      gdot += __shfl_xor(gdot, off, 64);
    }
    float att = __expf(s * SC_C - mi) * linv;
    float gs = att * (gdot - Di) * SC_C;
    gq += gs * kd;
  }
  __shared__ float oacc[8][64];
  oacc[y][d] = gq;
  __syncthreads();
  if (y == 0) {
    float sum = 0.f;
    for (int w = 0; w < 8; w++) sum += oacc[w][d];
    GQ[rowi + d] = sum;
  }
}

// ---------------- attention backward: dk, dv (column-parallel) ----------------
__global__ __launch_bounds__(512) void attn_bwd_kv(const float* __restrict__ Q,
                                                   const float* __restrict__ K,
                                                   const float* __restrict__ V,
                                                   const float* __restrict__ G,
                                                   const float* __restrict__ mbuf,
                                                   const float* __restrict__ lbuf,
                                                   const float* __restrict__ Dv,
                                                   float* __restrict__ GK,
                                                   float* __restrict__ GV) {
  int j = blockIdx.x, bh = blockIdx.y;
  int b = bh / NH, h = bh % NH;
  int d = threadIdx.x, y = threadIdx.y;
  size_t rowj = (size_t)(b * S_LEN + j) * E_DIM + h * HD;
  float kd = K[rowj + d], vd = V[rowj + d];
  float gk = 0.f, gv = 0.f;
  for (int i = j + y; i < S_LEN; i += 8) {
    size_t rowi = (size_t)(b * S_LEN + i) * E_DIM + h * HD;
    float qd = Q[rowi + d], gd = G[rowi + d];
    float s = qd * kd, gdot = gd * vd;
    for (int off = 32; off; off >>= 1) {
      s += __shfl_xor(s, off, 64);
      gdot += __shfl_xor(gdot, off, 64);
    }
    size_t sid = (size_t)(b * NH + h) * S_LEN + i;
    float att = __expf(s * SC_C - mbuf[sid]) * lbuf[sid];
    float gs = att * (gdot - Dv[sid]) * SC_C;
    gv += att * gd;
    gk += gs * qd;
  }
  __shared__ float oa[8][64], ob[8][64];
  oa[y][d] = gk;
  ob[y][d] = gv;
  __syncthreads();
  if (y == 0) {
    float sk = 0.f, sv = 0.f;
    for (int w = 0; w < 8; w++) { sk += oa[w][d]; sv += ob[w][d]; }
    GK[rowj + d] = sk;
    GV[rowj + d] = sv;
  }
}

// ---------------- launch ----------------
extern "C" void kernel_launch(void* const* d_in, const int* in_sizes, int n_in,
                              void* d_out, int out_size, void* d_ws, size_t ws_size,
                              hipStream_t stream) {
  // All inputs and the output are fp32 (reference is pure float32).
  const float* T1 = (const float*)d_in[0];   // fc1_x [2048,1024] — stage-1 target
  const float* Wq = (const float*)d_in[1];
  const float* Wk = (const float*)d_in[2];
  const float* Wv = (const float*)d_in[3];
  const float* Wo = (const float*)d_in[4];

  const size_t M2 = 2097152;  // 2048*1024
  float* w = (float*)d_ws;
  float* Xs = w;              // stage-1 latent -> att_score (stage-2 target)
  float* R  = Xs + M2;        // residual / g
  float* Qb = R + M2;
  float* Kb = Qb + M2;
  float* Vb = Kb + M2;
  float* Ob = Vb + M2;
  float* GQ = Ob + M2;
  float* GK = GQ + M2;
  float* GV = GK + M2;
  float* mS = GV + M2;        // 32K
  float* lS = mS + 32768;     // 32K
  float* DvS = lS + 32768;    // 32K
  float* X2 = (float*)d_out;  // stage-2 latent accumulates directly into d_out

  dim3 cvt2((M2 + 255) / 256);
  hipMemsetAsync(Xs, 0, M2 * sizeof(float), stream);
  hipMemsetAsync(X2, 0, M2 * sizeof(float), stream);

  dim3 ggrid(8, 16);  // (N/128, M/128)

  // ---- stage 1: att_score = pc_infer(fc1_x, z -> z @ Wo^T), x in Xs ----
  for (int t = 0; t < 3; t++) {
    gemm128<1, 1><<<ggrid, 256, 0, stream>>>(Xs, Wo, R, T1, 0.f);       // R = T1 - Xs@Wo^T
    gemm128<0, 2><<<ggrid, 256, 0, stream>>>(R, Wo, Xs, nullptr, LR_C); // Xs += LR * R@Wo
  }

  // ---- stage 2: x_qkv = pc_infer(att_score, causal MHA), x in X2 (= d_out) ----
  dim3 agrid(S_LEN, BH_CNT), ablk(64, 8);
  for (int t = 0; t < 3; t++) {
    gemm128<1, 0><<<ggrid, 256, 0, stream>>>(X2, Wq, Qb, nullptr, 0.f);  // Q = X2@Wq^T
    gemm128<1, 0><<<ggrid, 256, 0, stream>>>(X2, Wk, Kb, nullptr, 0.f);  // K = X2@Wk^T
    gemm128<1, 0><<<ggrid, 256, 0, stream>>>(X2, Wv, Vb, nullptr, 0.f);  // V = X2@Wv^T
    attn_fwd<<<agrid, ablk, 0, stream>>>(Qb, Kb, Vb, Ob, mS, lS);
    k_sub<<<cvt2, 256, 0, stream>>>(Ob, Xs, R, (int)M2);                 // g = f(x) - target
    k_rowdot<<<M_ROWS * NH, 64, 0, stream>>>(R, Ob, DvS);                // D_i = g.o per row-head
    attn_bwd_q<<<agrid, ablk, 0, stream>>>(Qb, Kb, Vb, R, mS, lS, DvS, GQ);
    attn_bwd_kv<<<agrid, ablk, 0, stream>>>(Qb, Kb, Vb, R, mS, lS, DvS, GK, GV);
    gemm128<0, 2><<<ggrid, 256, 0, stream>>>(GQ, Wq, X2, nullptr, -LR_C);  // x -= LR*dq@Wq
    gemm128<0, 2><<<ggrid, 256, 0, stream>>>(GK, Wk, X2, nullptr, -LR_C);  // x -= LR*dk@Wk
    gemm128<0, 2><<<ggrid, 256, 0, stream>>>(GV, Wv, X2, nullptr, -LR_C);  // x -= LR*dv@Wv
  }
}

// Round 3
// 6259.473 us; speedup vs baseline: 3.2071x; 3.2071x over previous
//
#include <hip/hip_runtime.h>
#include <hip/hip_bf16.h>

// Problem constants (B=2, S=1024, E=1024, H=16, D=64)
#define S_LEN 1024
#define E_DIM 1024
#define NH 16
#define HD 64
#define M_ROWS 2048   // B*S
#define BH_CNT 32     // B*NH

static constexpr float LR_C = 0.01f;
static constexpr float SC_C = 0.125f;  // 1/sqrt(64)

// ---------------- fp32 tiled GEMM: C[M,N] op= A[M,K] * op(B) ----------------
// TRANSB=1: op(B)[k][n] = Bm[n*K+k]; TRANSB=0: op(B)[k][n] = Bm[k*N+n]
// MODE 0: C = acc;  MODE 1: C = T - acc;  MODE 2: C += alpha*acc
template <int TRANSB, int MODE>
__global__ __launch_bounds__(256) void gemm128(const float* __restrict__ A,
                                               const float* __restrict__ Bm,
                                               float* __restrict__ C,
                                               const float* __restrict__ T, float alpha) {
  const int K = 1024, N = 1024;
  __shared__ float As[16][128];
  __shared__ float Bs[16][128];
  int tid = threadIdx.x;
  int m0 = blockIdx.y * 128, n0 = blockIdx.x * 128;
  int tx = tid % 16, ty = tid / 16;
  float acc[8][8] = {};

  for (int k0 = 0; k0 < K; k0 += 16) {
    #pragma unroll
    for (int t = 0; t < 2; t++) {
      int idx = tid * 2 + t;
      int r = idx >> 2, kp = (idx & 3) * 4;
      float4 av = *(const float4*)(A + (size_t)(m0 + r) * K + k0 + kp);
      As[kp + 0][r] = av.x; As[kp + 1][r] = av.y;
      As[kp + 2][r] = av.z; As[kp + 3][r] = av.w;
    }
    if (TRANSB) {
      #pragma unroll
      for (int t = 0; t < 2; t++) {
        int idx = tid * 2 + t;
        int r = idx >> 2, kp = (idx & 3) * 4;
        float4 bv = *(const float4*)(Bm + (size_t)(n0 + r) * K + k0 + kp);
        Bs[kp + 0][r] = bv.x; Bs[kp + 1][r] = bv.y;
        Bs[kp + 2][r] = bv.z; Bs[kp + 3][r] = bv.w;
      }
    } else {
      #pragma unroll
      for (int t = 0; t < 2; t++) {
        int idx = tid * 2 + t;
        int kk = idx >> 5, c = (idx & 31) * 4;
        *(float4*)&Bs[kk][c] = *(const float4*)(Bm + (size_t)(k0 + kk) * N + n0 + c);
      }
    }
    __syncthreads();
    #pragma unroll
    for (int kk = 0; kk < 16; kk++) {
      float a[8], b[8];
      *(float4*)&a[0] = *(float4*)&As[kk][ty * 8];
      *(float4*)&a[4] = *(float4*)&As[kk][ty * 8 + 4];
      *(float4*)&b[0] = *(float4*)&Bs[kk][tx * 8];
      *(float4*)&b[4] = *(float4*)&Bs[kk][tx * 8 + 4];
      #pragma unroll
      for (int ii = 0; ii < 8; ii++)
        #pragma unroll
        for (int jj = 0; jj < 8; jj++) acc[ii][jj] += a[ii] * b[jj];
    }
    __syncthreads();
  }

  #pragma unroll
  for (int ii = 0; ii < 8; ii++) {
    size_t crow = (size_t)(m0 + ty * 8 + ii) * N + n0 + tx * 8;
    if (MODE == 0) {
      #pragma unroll
      for (int jj = 0; jj < 8; jj++) C[crow + jj] = acc[ii][jj];
    } else if (MODE == 1) {
      #pragma unroll
      for (int jj = 0; jj < 8; jj++) C[crow + jj] = T[crow + jj] - acc[ii][jj];
    } else {
      #pragma unroll
      for (int jj = 0; jj < 8; jj++) C[crow + jj] += alpha * acc[ii][jj];
    }
  }
}

// ====================== tiled attention ======================
// Per (b,h): Q/K/V/G rows at base + row*E_DIM, 64 cols.
// Tiles: i-tile 64 (fwd, bwd_q) or 32 (bwd_kv inner); j-tile 32.
// LDS layouts: [d][x] transposed tiles padded +2 (conflict-light stores, bcast float2 reads);
// row-major [r][64] tiles unpadded (bank-uniform); P/dS [i][j] padded +2
// (natural 4-way stores, broadcast scalar column reads).

// ---- fwd pass 1: per-row m and 1/l (online softmax partials + LDS merge) ----
// grid (16, 32) block 256; it reversed so big tiles dispatch first.
__global__ __launch_bounds__(256) void fwd_ml(const float* __restrict__ Q,
                                              const float* __restrict__ K,
                                              float* __restrict__ mbuf,
                                              float* __restrict__ lbuf) {
  int it = 15 - blockIdx.x;
  int bh = blockIdx.y, b = bh / NH, h = bh % NH;
  int tid = threadIdx.x, ty = tid >> 4, tx = tid & 15;
  __shared__ float Qs[64][66];
  __shared__ float Ks[64][34];
  size_t base = (size_t)b * S_LEN * E_DIM + h * HD;
  int i0 = it * 64;

  #pragma unroll
  for (int t = 0; t < 4; t++) {
    int lin = tid + 256 * t;
    int r = lin >> 4, dc = (lin & 15) << 2;
    float4 v = *(const float4*)(Q + base + (size_t)(i0 + r) * E_DIM + dc);
    Qs[dc][r] = v.x; Qs[dc + 1][r] = v.y; Qs[dc + 2][r] = v.z; Qs[dc + 3][r] = v.w;
  }
  float m_r[4], l_r[4];
  #pragma unroll
  for (int ii = 0; ii < 4; ii++) { m_r[ii] = -1e30f; l_r[ii] = 0.f; }

  int njt = 2 * it + 2;
  for (int jt = 0; jt < njt; jt++) {
    int j0 = jt * 32;
    __syncthreads();
    #pragma unroll
    for (int t = 0; t < 2; t++) {
      int lin = tid + 256 * t;
      int r = lin >> 4, dc = (lin & 15) << 2;
      float4 v = *(const float4*)(K + base + (size_t)(j0 + r) * E_DIM + dc);
      Ks[dc][r] = v.x; Ks[dc + 1][r] = v.y; Ks[dc + 2][r] = v.z; Ks[dc + 3][r] = v.w;
    }
    __syncthreads();
    float s[4][2] = {};
    #pragma unroll 8
    for (int d = 0; d < 64; d++) {
      float2 qa = *(const float2*)&Qs[d][ty * 4];
      float2 qb = *(const float2*)&Qs[d][ty * 4 + 2];
      float2 kk = *(const float2*)&Ks[d][tx * 2];
      s[0][0] += qa.x * kk.x; s[0][1] += qa.x * kk.y;
      s[1][0] += qa.y * kk.x; s[1][1] += qa.y * kk.y;
      s[2][0] += qb.x * kk.x; s[2][1] += qb.x * kk.y;
      s[3][0] += qb.y * kk.x; s[3][1] += qb.y * kk.y;
    }
    #pragma unroll
    for (int ii = 0; ii < 4; ii++) {
      int ig = i0 + ty * 4 + ii;
      #pragma unroll
      for (int jj = 0; jj < 2; jj++) {
        int jg = j0 + tx * 2 + jj;
        if (jg <= ig) {
          float sv = s[ii][jj] * SC_C;
          float mn = fmaxf(m_r[ii], sv);
          l_r[ii] = l_r[ii] * __expf(m_r[ii] - mn) + __expf(sv - mn);
          m_r[ii] = mn;
        }
      }
    }
  }
  __syncthreads();
  float* sc = &Ks[0][0];  // scratch: 64 rows x 16 tx x 2
  #pragma unroll
  for (int ii = 0; ii < 4; ii++) {
    int r = ty * 4 + ii;
    sc[(r * 16 + tx) * 2] = m_r[ii];
    sc[(r * 16 + tx) * 2 + 1] = l_r[ii];
  }
  __syncthreads();
  if (tid < 64) {
    float m = -1e30f;
    for (int t = 0; t < 16; t++) m = fmaxf(m, sc[(tid * 16 + t) * 2]);
    float l = 0.f;
    for (int t = 0; t < 16; t++) l += sc[(tid * 16 + t) * 2 + 1] * __expf(sc[(tid * 16 + t) * 2] - m);
    size_t sid = (size_t)bh * S_LEN + i0 + tid;
    mbuf[sid] = m;
    lbuf[sid] = 1.0f / l;
  }
}

// ---- fwd pass 2: O = P V; fused R = O - target and Dv = rowdot(R, O) ----
__global__ __launch_bounds__(256) void fwd_o(const float* __restrict__ Q,
                                             const float* __restrict__ K,
                                             const float* __restrict__ V,
                                             const float* __restrict__ Xs,
                                             const float* __restrict__ mbuf,
                                             const float* __restrict__ lbuf,
                                             float* __restrict__ Rg,
                                             float* __restrict__ Dv) {
  int it = 15 - blockIdx.x;
  int bh = blockIdx.y, b = bh / NH, h = bh % NH;
  int tid = threadIdx.x, ty = tid >> 4, tx = tid & 15;
  __shared__ float Qs[64][66];
  __shared__ float Ks[64][34];
  __shared__ float Ps[64][34];   // [i][j]
  __shared__ float Vrm[32][64];  // [j][d]
  size_t base = (size_t)b * S_LEN * E_DIM + h * HD;
  int i0 = it * 64;

  #pragma unroll
  for (int t = 0; t < 4; t++) {
    int lin = tid + 256 * t;
    int r = lin >> 4, dc = (lin & 15) << 2;
    float4 v = *(const float4*)(Q + base + (size_t)(i0 + r) * E_DIM + dc);
    Qs[dc][r] = v.x; Qs[dc + 1][r] = v.y; Qs[dc + 2][r] = v.z; Qs[dc + 3][r] = v.w;
  }
  float mrow[4], lrow[4];
  #pragma unroll
  for (int ii = 0; ii < 4; ii++) {
    size_t sid = (size_t)bh * S_LEN + i0 + ty * 4 + ii;
    mrow[ii] = mbuf[sid]; lrow[ii] = lbuf[sid];
  }
  float o[4][4] = {};

  int njt = 2 * it + 2;
  for (int jt = 0; jt < njt; jt++) {
    int j0 = jt * 32;
    __syncthreads();
    #pragma unroll
    for (int t = 0; t < 2; t++) {
      int lin = tid + 256 * t;
      int r = lin >> 4, dc = (lin & 15) << 2;
      float4 v = *(const float4*)(K + base + (size_t)(j0 + r) * E_DIM + dc);
      Ks[dc][r] = v.x; Ks[dc + 1][r] = v.y; Ks[dc + 2][r] = v.z; Ks[dc + 3][r] = v.w;
      *(float4*)&Vrm[r][dc] = *(const float4*)(V + base + (size_t)(j0 + r) * E_DIM + dc);
    }
    __syncthreads();
    float s[4][2] = {};
    #pragma unroll 8
    for (int d = 0; d < 64; d++) {
      float2 qa = *(const float2*)&Qs[d][ty * 4];
      float2 qb = *(const float2*)&Qs[d][ty * 4 + 2];
      float2 kk = *(const float2*)&Ks[d][tx * 2];
      s[0][0] += qa.x * kk.x; s[0][1] += qa.x * kk.y;
      s[1][0] += qa.y * kk.x; s[1][1] += qa.y * kk.y;
      s[2][0] += qb.x * kk.x; s[2][1] += qb.x * kk.y;
      s[3][0] += qb.y * kk.x; s[3][1] += qb.y * kk.y;
    }
    #pragma unroll
    for (int ii = 0; ii < 4; ii++) {
      int ig = i0 + ty * 4 + ii;
      #pragma unroll
      for (int jj = 0; jj < 2; jj++) {
        int jg = j0 + tx * 2 + jj;
        float P = 0.f;
        if (jg <= ig) P = __expf(s[ii][jj] * SC_C - mrow[ii]) * lrow[ii];
        Ps[ty * 4 + ii][tx * 2 + jj] = P;
      }
    }
    __syncthreads();
    #pragma unroll 4
    for (int j = 0; j < 32; j++) {
      float4 v4 = *(const float4*)&Vrm[j][tx * 4];
      float p0 = Ps[ty * 4 + 0][j], p1 = Ps[ty * 4 + 1][j];
      float p2 = Ps[ty * 4 + 2][j], p3 = Ps[ty * 4 + 3][j];
      o[0][0] += p0 * v4.x; o[0][1] += p0 * v4.y; o[0][2] += p0 * v4.z; o[0][3] += p0 * v4.w;
      o[1][0] += p1 * v4.x; o[1][1] += p1 * v4.y; o[1][2] += p1 * v4.z; o[1][3] += p1 * v4.w;
      o[2][0] += p2 * v4.x; o[2][1] += p2 * v4.y; o[2][2] += p2 * v4.z; o[2][3] += p2 * v4.w;
      o[3][0] += p3 * v4.x; o[3][1] += p3 * v4.y; o[3][2] += p3 * v4.z; o[3][3] += p3 * v4.w;
    }
  }
  // epilogue: g = o - Xs, write Rg, partial row-dots
  float dpart[4];
  #pragma unroll
  for (int ii = 0; ii < 4; ii++) {
    size_t gi = base + (size_t)(i0 + ty * 4 + ii) * E_DIM + tx * 4;
    float4 xv = *(const float4*)(Xs + gi);
    float4 g;
    g.x = o[ii][0] - xv.x; g.y = o[ii][1] - xv.y;
    g.z = o[ii][2] - xv.z; g.w = o[ii][3] - xv.w;
    *(float4*)(Rg + gi) = g;
    dpart[ii] = g.x * o[ii][0] + g.y * o[ii][1] + g.z * o[ii][2] + g.w * o[ii][3];
  }
  __syncthreads();
  float* sc = &Ks[0][0];  // 64 rows x 16 tx
  #pragma unroll
  for (int ii = 0; ii < 4; ii++) sc[(ty * 4 + ii) * 16 + tx] = dpart[ii];
  __syncthreads();
  if (tid < 64) {
    float sum = 0.f;
    for (int t = 0; t < 16; t++) sum += sc[tid * 16 + t];
    Dv[(size_t)bh * S_LEN + i0 + tid] = sum;
  }
}

// ---- bwd dq: per (bh, i-tile 64), loop j-tiles 32 ----
__global__ __launch_bounds__(256) void bwd_q(const float* __restrict__ Q,
                                             const float* __restrict__ K,
                                             const float* __restrict__ V,
                                             const float* __restrict__ G,
                                             const float* __restrict__ mbuf,
                                             const float* __restrict__ lbuf,
                                             const float* __restrict__ Dv,
                                             float* __restrict__ GQ) {
  int it = 15 - blockIdx.x;
  int bh = blockIdx.y, b = bh / NH, h = bh % NH;
  int tid = threadIdx.x, ty = tid >> 4, tx = tid & 15;
  __shared__ float Qs[64][66];   // [d][i]
  __shared__ float Gs[64][66];   // [d][i]
  __shared__ float Ks[64][34];   // [d][j]
  __shared__ float VdS[64][34];  // phase1: Vs [d][j] (rows 0..63 d); phase2: dSs [i][j]
  __shared__ float Krm[32][64];  // [j][d]
  size_t base = (size_t)b * S_LEN * E_DIM + h * HD;
  int i0 = it * 64;

  #pragma unroll
  for (int t = 0; t < 4; t++) {
    int lin = tid + 256 * t;
    int r = lin >> 4, dc = (lin & 15) << 2;
    float4 v = *(const float4*)(Q + base + (size_t)(i0 + r) * E_DIM + dc);
    Qs[dc][r] = v.x; Qs[dc + 1][r] = v.y; Qs[dc + 2][r] = v.z; Qs[dc + 3][r] = v.w;
    float4 g = *(const float4*)(G + base + (size_t)(i0 + r) * E_DIM + dc);
    Gs[dc][r] = g.x; Gs[dc + 1][r] = g.y; Gs[dc + 2][r] = g.z; Gs[dc + 3][r] = g.w;
  }
  float mrow[4], lrow[4], drow[4];
  #pragma unroll
  for (int ii = 0; ii < 4; ii++) {
    size_t sid = (size_t)bh * S_LEN + i0 + ty * 4 + ii;
    mrow[ii] = mbuf[sid]; lrow[ii] = lbuf[sid]; drow[ii] = Dv[sid];
  }
  float dq[4][4] = {};

  int njt = 2 * it + 2;
  for (int jt = 0; jt < njt; jt++) {
    int j0 = jt * 32;
    __syncthreads();
    #pragma unroll
    for (int t = 0; t < 2; t++) {
      int lin = tid + 256 * t;
      int r = lin >> 4, dc = (lin & 15) << 2;
      float4 kv = *(const float4*)(K + base + (size_t)(j0 + r) * E_DIM + dc);
      Ks[dc][r] = kv.x; Ks[dc + 1][r] = kv.y; Ks[dc + 2][r] = kv.z; Ks[dc + 3][r] = kv.w;
      float4 vv = *(const float4*)(V + base + (size_t)(j0 + r) * E_DIM + dc);
      VdS[dc][r] = vv.x; VdS[dc + 1][r] = vv.y; VdS[dc + 2][r] = vv.z; VdS[dc + 3][r] = vv.w;
      *(float4*)&Krm[r][dc] = kv;
    }
    __syncthreads();
    float s[4][2] = {}, dp[4][2] = {};
    #pragma unroll 4
    for (int d = 0; d < 64; d++) {
      float2 qa = *(const float2*)&Qs[d][ty * 4];
      float2 qb = *(const float2*)&Qs[d][ty * 4 + 2];
      float2 ga = *(const float2*)&Gs[d][ty * 4];
      float2 gb = *(const float2*)&Gs[d][ty * 4 + 2];
      float2 kk = *(const float2*)&Ks[d][tx * 2];
      float2 vv = *(const float2*)&VdS[d][tx * 2];
      s[0][0] += qa.x * kk.x; s[0][1] += qa.x * kk.y;
      s[1][0] += qa.y * kk.x; s[1][1] += qa.y * kk.y;
      s[2][0] += qb.x * kk.x; s[2][1] += qb.x * kk.y;
      s[3][0] += qb.y * kk.x; s[3][1] += qb.y * kk.y;
      dp[0][0] += ga.x * vv.x; dp[0][1] += ga.x * vv.y;
      dp[1][0] += ga.y * vv.x; dp[1][1] += ga.y * vv.y;
      dp[2][0] += gb.x * vv.x; dp[2][1] += gb.x * vv.y;
      dp[3][0] += gb.y * vv.x; dp[3][1] += gb.y * vv.y;
    }
    __syncthreads();  // all reads of Vs done before overwrite as dSs
    #pragma unroll
    for (int ii = 0; ii < 4; ii++) {
      int ig = i0 + ty * 4 + ii;
      #pragma unroll
      for (int jj = 0; jj < 2; jj++) {
        int jg = j0 + tx * 2 + jj;
        float dsv = 0.f;
        if (jg <= ig) {
          float P = __expf(s[ii][jj] * SC_C - mrow[ii]) * lrow[ii];
          dsv = P * (dp[ii][jj] - drow[ii]) * SC_C;
        }
        VdS[ty * 4 + ii][tx * 2 + jj] = dsv;
      }
    }
    __syncthreads();
    #pragma unroll 4
    for (int j = 0; j < 32; j++) {
      float4 k4 = *(const float4*)&Krm[j][tx * 4];
      float d0 = VdS[ty * 4 + 0][j], d1 = VdS[ty * 4 + 1][j];
      float d2 = VdS[ty * 4 + 2][j], d3 = VdS[ty * 4 + 3][j];
      dq[0][0] += d0 * k4.x; dq[0][1] += d0 * k4.y; dq[0][2] += d0 * k4.z; dq[0][3] += d0 * k4.w;
      dq[1][0] += d1 * k4.x; dq[1][1] += d1 * k4.y; dq[1][2] += d1 * k4.z; dq[1][3] += d1 * k4.w;
      dq[2][0] += d2 * k4.x; dq[2][1] += d2 * k4.y; dq[2][2] += d2 * k4.z; dq[2][3] += d2 * k4.w;
      dq[3][0] += d3 * k4.x; dq[3][1] += d3 * k4.y; dq[3][2] += d3 * k4.z; dq[3][3] += d3 * k4.w;
    }
  }
  #pragma unroll
  for (int ii = 0; ii < 4; ii++) {
    size_t gi = base + (size_t)(i0 + ty * 4 + ii) * E_DIM + tx * 4;
    float4 w; w.x = dq[ii][0]; w.y = dq[ii][1]; w.z = dq[ii][2]; w.w = dq[ii][3];
    *(float4*)(GQ + gi) = w;
  }
}

// ---- bwd dk/dv: per (bh, j-tile 32), loop i-tiles 32 ----
__global__ __launch_bounds__(256) void bwd_kv(const float* __restrict__ Q,
                                              const float* __restrict__ K,
                                              const float* __restrict__ V,
                                              const float* __restrict__ G,
                                              const float* __restrict__ mbuf,
                                              const float* __restrict__ lbuf,
                                              const float* __restrict__ Dv,
                                              float* __restrict__ GK,
                                              float* __restrict__ GV) {
  int jt = blockIdx.x;  // jt=0 has the most work and dispatches first
  int bh = blockIdx.y, b = bh / NH, h = bh % NH;
  int tid = threadIdx.x, ty = tid >> 4, tx = tid & 15;
  __shared__ float Ks[64][34];   // [d][j]
  __shared__ float Vs[64][34];   // [d][j]
  __shared__ float Qs[64][34];   // [d][i]
  __shared__ float Gs[64][34];   // [d][i]
  __shared__ float Qrm[32][64];  // [i][d]
  __shared__ float Grm[32][64];  // [i][d]
  __shared__ float Ps[32][34];   // [i][j]
  __shared__ float dSs[32][34];  // [i][j]
  size_t base = (size_t)b * S_LEN * E_DIM + h * HD;
  int j0 = jt * 32;

  #pragma unroll
  for (int t = 0; t < 2; t++) {
    int lin = tid + 256 * t;
    int r = lin >> 4, dc = (lin & 15) << 2;
    float4 kv = *(const float4*)(K + base + (size_t)(j0 + r) * E_DIM + dc);
    Ks[dc][r] = kv.x; Ks[dc + 1][r] = kv.y; Ks[dc + 2][r] = kv.z; Ks[dc + 3][r] = kv.w;
    float4 vv = *(const float4*)(V + base + (size_t)(j0 + r) * E_DIM + dc);
    Vs[dc][r] = vv.x; Vs[dc + 1][r] = vv.y; Vs[dc + 2][r] = vv.z; Vs[dc + 3][r] = vv.w;
  }
  float dk[2][4] = {}, dv[2][4] = {};  // rows j0+ty*2+jj, cols tx*4+dd

  for (int i_t = jt; i_t < 32; i_t++) {
    int i0 = i_t * 32;
    __syncthreads();
    #pragma unroll
    for (int t = 0; t < 2; t++) {
      int lin = tid + 256 * t;
      int r = lin >> 4, dc = (lin & 15) << 2;
      float4 qv = *(const float4*)(Q + base + (size_t)(i0 + r) * E_DIM + dc);
      Qs[dc][r] = qv.x; Qs[dc + 1][r] = qv.y; Qs[dc + 2][r] = qv.z; Qs[dc + 3][r] = qv.w;
      float4 gv = *(const float4*)(G + base + (size_t)(i0 + r) * E_DIM + dc);
      Gs[dc][r] = gv.x; Gs[dc + 1][r] = gv.y; Gs[dc + 2][r] = gv.z; Gs[dc + 3][r] = gv.w;
      *(float4*)&Qrm[r][dc] = qv;
      *(float4*)&Grm[r][dc] = gv;
    }
    __syncthreads();
    float mr[2], lr[2], dr[2];
    #pragma unroll
    for (int il = 0; il < 2; il++) {
      size_t sid = (size_t)bh * S_LEN + i0 + ty * 2 + il;
      mr[il] = mbuf[sid]; lr[il] = lbuf[sid]; dr[il] = Dv[sid];
    }
    float s[2][2] = {}, dp[2][2] = {};
    #pragma unroll 4
    for (int d = 0; d < 64; d++) {
      float2 q = *(const float2*)&Qs[d][ty * 2];
      float2 g = *(const float2*)&Gs[d][ty * 2];
      float2 kk = *(const float2*)&Ks[d][tx * 2];
      float2 vv = *(const float2*)&Vs[d][tx * 2];
      s[0][0] += q.x * kk.x; s[0][1] += q.x * kk.y;
      s[1][0] += q.y * kk.x; s[1][1] += q.y * kk.y;
      dp[0][0] += g.x * vv.x; dp[0][1] += g.x * vv.y;
      dp[1][0] += g.y * vv.x; dp[1][1] += g.y * vv.y;
    }
    #pragma unroll
    for (int il = 0; il < 2; il++) {
      int ig = i0 + ty * 2 + il;
      #pragma unroll
      for (int jl = 0; jl < 2; jl++) {
        int jg = j0 + tx * 2 + jl;
        float P = 0.f, dsv = 0.f;
        if (ig >= jg) {
          P = __expf(s[il][jl] * SC_C - mr[il]) * lr[il];
          dsv = P * (dp[il][jl] - dr[il]) * SC_C;
        }
        Ps[ty * 2 + il][tx * 2 + jl] = P;
        dSs[ty * 2 + il][tx * 2 + jl] = dsv;
      }
    }
    __syncthreads();
    #pragma unroll 4
    for (int i_l = 0; i_l < 32; i_l++) {
      float2 p2 = *(const float2*)&Ps[i_l][ty * 2];
      float2 d2 = *(const float2*)&dSs[i_l][ty * 2];
      float4 g4 = *(const float4*)&Grm[i_l][tx * 4];
      float4 q4 = *(const float4*)&Qrm[i_l][tx * 4];
      dv[0][0] += p2.x * g4.x; dv[0][1] += p2.x * g4.y; dv[0][2] += p2.x * g4.z; dv[0][3] += p2.x * g4.w;
      dv[1][0] += p2.y * g4.x; dv[1][1] += p2.y * g4.y; dv[1][2] += p2.y * g4.z; dv[1][3] += p2.y * g4.w;
      dk[0][0] += d2.x * q4.x; dk[0][1] += d2.x * q4.y; dk[0][2] += d2.x * q4.z; dk[0][3] += d2.x * q4.w;
      dk[1][0] += d2.y * q4.x; dk[1][1] += d2.y * q4.y; dk[1][2] += d2.y * q4.z; dk[1][3] += d2.y * q4.w;
    }
  }
  #pragma unroll
  for (int jj = 0; jj < 2; jj++) {
    size_t gi = base + (size_t)(j0 + ty * 2 + jj) * E_DIM + tx * 4;
    float4 wk; wk.x = dk[jj][0]; wk.y = dk[jj][1]; wk.z = dk[jj][2]; wk.w = dk[jj][3];
    float4 wv; wv.x = dv[jj][0]; wv.y = dv[jj][1]; wv.z = dv[jj][2]; wv.w = dv[jj][3];
    *(float4*)(GK + gi) = wk;
    *(float4*)(GV + gi) = wv;
  }
}

// ---------------- launch ----------------
extern "C" void kernel_launch(void* const* d_in, const int* in_sizes, int n_in,
                              void* d_out, int out_size, void* d_ws, size_t ws_size,
                              hipStream_t stream) {
  const float* T1 = (const float*)d_in[0];   // fc1_x — stage-1 target
  const float* Wq = (const float*)d_in[1];
  const float* Wk = (const float*)d_in[2];
  const float* Wv = (const float*)d_in[3];
  const float* Wo = (const float*)d_in[4];

  const size_t M2 = 2097152;  // 2048*1024
  float* w = (float*)d_ws;
  float* Xs = w;              // stage-1 latent -> att_score (stage-2 target)
  float* R  = Xs + M2;        // residual / g
  float* Qb = R + M2;
  float* Kb = Qb + M2;
  float* Vb = Kb + M2;
  float* GQ = Vb + M2;
  float* GK = GQ + M2;
  float* GV = GK + M2;
  float* mS = GV + M2;        // 32K
  float* lS = mS + 32768;     // 32K
  float* DvS = lS + 32768;    // 32K
  float* X2 = (float*)d_out;  // stage-2 latent accumulates directly into d_out

  hipMemsetAsync(Xs, 0, M2 * sizeof(float), stream);
  hipMemsetAsync(X2, 0, M2 * sizeof(float), stream);

  dim3 ggrid(8, 16);  // (N/128, M/128)

  // ---- stage 1: att_score = pc_infer(fc1_x, z -> z @ Wo^T) ----
  for (int t = 0; t < 3; t++) {
    gemm128<1, 1><<<ggrid, 256, 0, stream>>>(Xs, Wo, R, T1, 0.f);       // R = T1 - Xs@Wo^T
    gemm128<0, 2><<<ggrid, 256, 0, stream>>>(R, Wo, Xs, nullptr, LR_C); // Xs += LR * R@Wo
  }

  // ---- stage 2: x_qkv = pc_infer(att_score, causal MHA) ----
  dim3 agrid(16, BH_CNT), kvgrid(32, BH_CNT);
  for (int t = 0; t < 3; t++) {
    gemm128<1, 0><<<ggrid, 256, 0, stream>>>(X2, Wq, Qb, nullptr, 0.f);
    gemm128<1, 0><<<ggrid, 256, 0, stream>>>(X2, Wk, Kb, nullptr, 0.f);
    gemm128<1, 0><<<ggrid, 256, 0, stream>>>(X2, Wv, Vb, nullptr, 0.f);
    fwd_ml<<<agrid, 256, 0, stream>>>(Qb, Kb, mS, lS);
    fwd_o<<<agrid, 256, 0, stream>>>(Qb, Kb, Vb, Xs, mS, lS, R, DvS);   // R = O - Xs, Dv fused
    bwd_q<<<agrid, 256, 0, stream>>>(Qb, Kb, Vb, R, mS, lS, DvS, GQ);
    bwd_kv<<<kvgrid, 256, 0, stream>>>(Qb, Kb, Vb, R, mS, lS, DvS, GK, GV);
    gemm128<0, 2><<<ggrid, 256, 0, stream>>>(GQ, Wq, X2, nullptr, -LR_C);
    gemm128<0, 2><<<ggrid, 256, 0, stream>>>(GK, Wk, X2, nullptr, -LR_C);
    gemm128<0, 2><<<ggrid, 256, 0, stream>>>(GV, Wv, X2, nullptr, -LR_C);
  }
}

// Round 4
// 3192.040 us; speedup vs baseline: 6.2890x; 1.9610x over previous
//
#include <hip/hip_runtime.h>
#include <hip/hip_bf16.h>

// Problem constants (B=2, S=1024, E=1024, H=16, D=64)
#define S_LEN 1024
#define E_DIM 1024
#define NH 16
#define HD 64
#define M_ROWS 2048   // B*S
#define BH_CNT 32     // B*NH

static constexpr float LR_C = 0.01f;
static constexpr float SC_C = 0.125f;  // 1/sqrt(64)

typedef unsigned short ushort_t;
typedef __attribute__((ext_vector_type(8))) __bf16 bf16x8;
typedef __attribute__((ext_vector_type(4))) float f32x4;

static __device__ inline ushort_t f2bu(float f) {
  __hip_bfloat16 h = __float2bfloat16(f);
  return *(ushort_t*)&h;
}

// ---------------- weight prep: bf16 cast + bf16 transpose, 64x64 tiles ----------------
__global__ __launch_bounds__(256) void prep_w(const float* __restrict__ W,
                                              ushort_t* __restrict__ Wb,
                                              ushort_t* __restrict__ WTb) {
  __shared__ float ts[64][65];
  int bx = blockIdx.x * 64, by = blockIdx.y * 64;  // col0, row0
  int t = threadIdx.x;
  int rr = t >> 6, cc = t & 63;
  #pragma unroll
  for (int p = 0; p < 16; p++) {
    int r = p * 4 + rr;
    float v = W[(size_t)(by + r) * E_DIM + bx + cc];
    ts[r][cc] = v;
    Wb[(size_t)(by + r) * E_DIM + bx + cc] = f2bu(v);
  }
  __syncthreads();
  #pragma unroll
  for (int p = 0; p < 16; p++) {
    int r = p * 4 + rr;
    WTb[(size_t)(bx + r) * E_DIM + by + cc] = f2bu(ts[cc][r]);
  }
}

// ---------------- bf16 MFMA GEMM: C[M,N] (M=2048, N=1024), A[M,K] bf16, B[N,K] bf16 ----
// Tile 64(M) x 128(N), BK=32, 256 threads = 4 waves in 2x2, each wave 32x64 (2x4 MFMAs).
// MODE 0: C_z = acc (fp32), z = blockIdx.z selects (B,C) of 3  [QKV projection]
// MODE 1: Cb = bf16(T - acc)                                    [stage-1 residual]
// MODE 2: C0 += alpha*acc (fp32) and Cb = bf16(C0), NSEG K-segments [PC update]
template <int MODE, int NSEG>
__global__ __launch_bounds__(256) void gemm_mf(
    const ushort_t* __restrict__ A0, const ushort_t* __restrict__ A1, const ushort_t* __restrict__ A2,
    const ushort_t* __restrict__ B0, const ushort_t* __restrict__ B1, const ushort_t* __restrict__ B2,
    float* __restrict__ C0, float* __restrict__ C1, float* __restrict__ C2,
    const float* __restrict__ T, __hip_bfloat16* __restrict__ Cb, float alpha) {
  const int K = 1024;
  __shared__ __bf16 As[64][40];    // +8 pad: 80B row stride -> 2-way banks (free)
  __shared__ __bf16 Bs[128][40];
  int tid = threadIdx.x;
  int m0 = blockIdx.y * 64, n0 = blockIdx.x * 128;

  const ushort_t* Bsel = B0;
  float* Cp = C0;
  if (MODE == 0) {
    int z = blockIdx.z;
    Bsel = (z == 0) ? B0 : (z == 1) ? B1 : B2;
    Cp = (z == 0) ? C0 : (z == 1) ? C1 : C2;
  }

  int lane = tid & 63, wave = tid >> 6;
  int wrow = wave >> 1, wcol = wave & 1;
  int fr = lane & 15, q = lane >> 4;

  f32x4 acc[2][4] = {};

  int ar = tid >> 2, ac = (tid & 3) * 8;  // staging: row, k-offset (8 bf16 = 16B)
  #pragma unroll 1
  for (int seg = 0; seg < NSEG; seg++) {
    const ushort_t* Aseg = (seg == 0) ? A0 : (seg == 1) ? A1 : A2;
    const ushort_t* Bseg = (MODE == 0) ? Bsel : ((seg == 0) ? B0 : (seg == 1) ? B1 : B2);
    const ushort_t* Ag = Aseg + (size_t)(m0 + ar) * K + ac;
    const ushort_t* Bg0 = Bseg + (size_t)(n0 + ar) * K + ac;
    const ushort_t* Bg1 = Bseg + (size_t)(n0 + 64 + ar) * K + ac;
    for (int k0 = 0; k0 < K; k0 += 32) {
      uint4 av = *(const uint4*)(Ag + k0);
      uint4 bv0 = *(const uint4*)(Bg0 + k0);
      uint4 bv1 = *(const uint4*)(Bg1 + k0);
      __syncthreads();  // previous iter's LDS reads complete
      *(uint4*)&As[ar][ac] = av;
      *(uint4*)&Bs[ar][ac] = bv0;
      *(uint4*)&Bs[64 + ar][ac] = bv1;
      __syncthreads();
      bf16x8 a0 = *(const bf16x8*)&As[wrow * 32 + fr][q * 8];
      bf16x8 a1 = *(const bf16x8*)&As[wrow * 32 + 16 + fr][q * 8];
      bf16x8 b0 = *(const bf16x8*)&Bs[wcol * 64 + fr][q * 8];
      bf16x8 b1 = *(const bf16x8*)&Bs[wcol * 64 + 16 + fr][q * 8];
      bf16x8 b2 = *(const bf16x8*)&Bs[wcol * 64 + 32 + fr][q * 8];
      bf16x8 b3 = *(const bf16x8*)&Bs[wcol * 64 + 48 + fr][q * 8];
      acc[0][0] = __builtin_amdgcn_mfma_f32_16x16x32_bf16(a0, b0, acc[0][0], 0, 0, 0);
      acc[0][1] = __builtin_amdgcn_mfma_f32_16x16x32_bf16(a0, b1, acc[0][1], 0, 0, 0);
      acc[0][2] = __builtin_amdgcn_mfma_f32_16x16x32_bf16(a0, b2, acc[0][2], 0, 0, 0);
      acc[0][3] = __builtin_amdgcn_mfma_f32_16x16x32_bf16(a0, b3, acc[0][3], 0, 0, 0);
      acc[1][0] = __builtin_amdgcn_mfma_f32_16x16x32_bf16(a1, b0, acc[1][0], 0, 0, 0);
      acc[1][1] = __builtin_amdgcn_mfma_f32_16x16x32_bf16(a1, b1, acc[1][1], 0, 0, 0);
      acc[1][2] = __builtin_amdgcn_mfma_f32_16x16x32_bf16(a1, b2, acc[1][2], 0, 0, 0);
      acc[1][3] = __builtin_amdgcn_mfma_f32_16x16x32_bf16(a1, b3, acc[1][3], 0, 0, 0);
    }
  }

  // C/D layout: col = lane&15, row = (lane>>4)*4 + reg  [m89/m91 verified]
  #pragma unroll
  for (int mi = 0; mi < 2; mi++)
    #pragma unroll
    for (int ni = 0; ni < 4; ni++) {
      int col = n0 + wcol * 64 + ni * 16 + fr;
      int row0 = m0 + wrow * 32 + mi * 16 + q * 4;
      #pragma unroll
      for (int r = 0; r < 4; r++) {
        size_t idx = (size_t)(row0 + r) * E_DIM + col;
        float v = acc[mi][ni][r];
        if (MODE == 0) {
          Cp[idx] = v;
        } else if (MODE == 1) {
          Cb[idx] = __float2bfloat16(T[idx] - v);
        } else {
          float nv = C0[idx] + alpha * v;
          C0[idx] = nv;
          Cb[idx] = __float2bfloat16(nv);
        }
      }
    }
}

// ====================== tiled attention (fp32, unchanged from R3) ======================

// ---- fwd pass 1: per-row m and 1/l ----
__global__ __launch_bounds__(256) void fwd_ml(const float* __restrict__ Q,
                                              const float* __restrict__ K,
                                              float* __restrict__ mbuf,
                                              float* __restrict__ lbuf) {
  int it = 15 - blockIdx.x;
  int bh = blockIdx.y, b = bh / NH, h = bh % NH;
  int tid = threadIdx.x, ty = tid >> 4, tx = tid & 15;
  __shared__ float Qs[64][66];
  __shared__ float Ks[64][34];
  size_t base = (size_t)b * S_LEN * E_DIM + h * HD;
  int i0 = it * 64;

  #pragma unroll
  for (int t = 0; t < 4; t++) {
    int lin = tid + 256 * t;
    int r = lin >> 4, dc = (lin & 15) << 2;
    float4 v = *(const float4*)(Q + base + (size_t)(i0 + r) * E_DIM + dc);
    Qs[dc][r] = v.x; Qs[dc + 1][r] = v.y; Qs[dc + 2][r] = v.z; Qs[dc + 3][r] = v.w;
  }
  float m_r[4], l_r[4];
  #pragma unroll
  for (int ii = 0; ii < 4; ii++) { m_r[ii] = -1e30f; l_r[ii] = 0.f; }

  int njt = 2 * it + 2;
  for (int jt = 0; jt < njt; jt++) {
    int j0 = jt * 32;
    __syncthreads();
    #pragma unroll
    for (int t = 0; t < 2; t++) {
      int lin = tid + 256 * t;
      int r = lin >> 4, dc = (lin & 15) << 2;
      float4 v = *(const float4*)(K + base + (size_t)(j0 + r) * E_DIM + dc);
      Ks[dc][r] = v.x; Ks[dc + 1][r] = v.y; Ks[dc + 2][r] = v.z; Ks[dc + 3][r] = v.w;
    }
    __syncthreads();
    float s[4][2] = {};
    #pragma unroll 8
    for (int d = 0; d < 64; d++) {
      float2 qa = *(const float2*)&Qs[d][ty * 4];
      float2 qb = *(const float2*)&Qs[d][ty * 4 + 2];
      float2 kk = *(const float2*)&Ks[d][tx * 2];
      s[0][0] += qa.x * kk.x; s[0][1] += qa.x * kk.y;
      s[1][0] += qa.y * kk.x; s[1][1] += qa.y * kk.y;
      s[2][0] += qb.x * kk.x; s[2][1] += qb.x * kk.y;
      s[3][0] += qb.y * kk.x; s[3][1] += qb.y * kk.y;
    }
    #pragma unroll
    for (int ii = 0; ii < 4; ii++) {
      int ig = i0 + ty * 4 + ii;
      #pragma unroll
      for (int jj = 0; jj < 2; jj++) {
        int jg = j0 + tx * 2 + jj;
        if (jg <= ig) {
          float sv = s[ii][jj] * SC_C;
          float mn = fmaxf(m_r[ii], sv);
          l_r[ii] = l_r[ii] * __expf(m_r[ii] - mn) + __expf(sv - mn);
          m_r[ii] = mn;
        }
      }
    }
  }
  __syncthreads();
  float* sc = &Ks[0][0];
  #pragma unroll
  for (int ii = 0; ii < 4; ii++) {
    int r = ty * 4 + ii;
    sc[(r * 16 + tx) * 2] = m_r[ii];
    sc[(r * 16 + tx) * 2 + 1] = l_r[ii];
  }
  __syncthreads();
  if (tid < 64) {
    float m = -1e30f;
    for (int t = 0; t < 16; t++) m = fmaxf(m, sc[(tid * 16 + t) * 2]);
    float l = 0.f;
    for (int t = 0; t < 16; t++) l += sc[(tid * 16 + t) * 2 + 1] * __expf(sc[(tid * 16 + t) * 2] - m);
    size_t sid = (size_t)bh * S_LEN + i0 + tid;
    mbuf[sid] = m;
    lbuf[sid] = 1.0f / l;
  }
}

// ---- fwd pass 2: O = P V; fused R = O - target and Dv = rowdot(R, O) ----
__global__ __launch_bounds__(256) void fwd_o(const float* __restrict__ Q,
                                             const float* __restrict__ K,
                                             const float* __restrict__ V,
                                             const float* __restrict__ Xs,
                                             const float* __restrict__ mbuf,
                                             const float* __restrict__ lbuf,
                                             float* __restrict__ Rg,
                                             float* __restrict__ Dv) {
  int it = 15 - blockIdx.x;
  int bh = blockIdx.y, b = bh / NH, h = bh % NH;
  int tid = threadIdx.x, ty = tid >> 4, tx = tid & 15;
  __shared__ float Qs[64][66];
  __shared__ float Ks[64][34];
  __shared__ float Ps[64][34];
  __shared__ float Vrm[32][64];
  size_t base = (size_t)b * S_LEN * E_DIM + h * HD;
  int i0 = it * 64;

  #pragma unroll
  for (int t = 0; t < 4; t++) {
    int lin = tid + 256 * t;
    int r = lin >> 4, dc = (lin & 15) << 2;
    float4 v = *(const float4*)(Q + base + (size_t)(i0 + r) * E_DIM + dc);
    Qs[dc][r] = v.x; Qs[dc + 1][r] = v.y; Qs[dc + 2][r] = v.z; Qs[dc + 3][r] = v.w;
  }
  float mrow[4], lrow[4];
  #pragma unroll
  for (int ii = 0; ii < 4; ii++) {
    size_t sid = (size_t)bh * S_LEN + i0 + ty * 4 + ii;
    mrow[ii] = mbuf[sid]; lrow[ii] = lbuf[sid];
  }
  float o[4][4] = {};

  int njt = 2 * it + 2;
  for (int jt = 0; jt < njt; jt++) {
    int j0 = jt * 32;
    __syncthreads();
    #pragma unroll
    for (int t = 0; t < 2; t++) {
      int lin = tid + 256 * t;
      int r = lin >> 4, dc = (lin & 15) << 2;
      float4 v = *(const float4*)(K + base + (size_t)(j0 + r) * E_DIM + dc);
      Ks[dc][r] = v.x; Ks[dc + 1][r] = v.y; Ks[dc + 2][r] = v.z; Ks[dc + 3][r] = v.w;
      *(float4*)&Vrm[r][dc] = *(const float4*)(V + base + (size_t)(j0 + r) * E_DIM + dc);
    }
    __syncthreads();
    float s[4][2] = {};
    #pragma unroll 8
    for (int d = 0; d < 64; d++) {
      float2 qa = *(const float2*)&Qs[d][ty * 4];
      float2 qb = *(const float2*)&Qs[d][ty * 4 + 2];
      float2 kk = *(const float2*)&Ks[d][tx * 2];
      s[0][0] += qa.x * kk.x; s[0][1] += qa.x * kk.y;
      s[1][0] += qa.y * kk.x; s[1][1] += qa.y * kk.y;
      s[2][0] += qb.x * kk.x; s[2][1] += qb.x * kk.y;
      s[3][0] += qb.y * kk.x; s[3][1] += qb.y * kk.y;
    }
    #pragma unroll
    for (int ii = 0; ii < 4; ii++) {
      int ig = i0 + ty * 4 + ii;
      #pragma unroll
      for (int jj = 0; jj < 2; jj++) {
        int jg = j0 + tx * 2 + jj;
        float P = 0.f;
        if (jg <= ig) P = __expf(s[ii][jj] * SC_C - mrow[ii]) * lrow[ii];
        Ps[ty * 4 + ii][tx * 2 + jj] = P;
      }
    }
    __syncthreads();
    #pragma unroll 4
    for (int j = 0; j < 32; j++) {
      float4 v4 = *(const float4*)&Vrm[j][tx * 4];
      float p0 = Ps[ty * 4 + 0][j], p1 = Ps[ty * 4 + 1][j];
      float p2 = Ps[ty * 4 + 2][j], p3 = Ps[ty * 4 + 3][j];
      o[0][0] += p0 * v4.x; o[0][1] += p0 * v4.y; o[0][2] += p0 * v4.z; o[0][3] += p0 * v4.w;
      o[1][0] += p1 * v4.x; o[1][1] += p1 * v4.y; o[1][2] += p1 * v4.z; o[1][3] += p1 * v4.w;
      o[2][0] += p2 * v4.x; o[2][1] += p2 * v4.y; o[2][2] += p2 * v4.z; o[2][3] += p2 * v4.w;
      o[3][0] += p3 * v4.x; o[3][1] += p3 * v4.y; o[3][2] += p3 * v4.z; o[3][3] += p3 * v4.w;
    }
  }
  float dpart[4];
  #pragma unroll
  for (int ii = 0; ii < 4; ii++) {
    size_t gi = base + (size_t)(i0 + ty * 4 + ii) * E_DIM + tx * 4;
    float4 xv = *(const float4*)(Xs + gi);
    float4 g;
    g.x = o[ii][0] - xv.x; g.y = o[ii][1] - xv.y;
    g.z = o[ii][2] - xv.z; g.w = o[ii][3] - xv.w;
    *(float4*)(Rg + gi) = g;
    dpart[ii] = g.x * o[ii][0] + g.y * o[ii][1] + g.z * o[ii][2] + g.w * o[ii][3];
  }
  __syncthreads();
  float* sc = &Ks[0][0];
  #pragma unroll
  for (int ii = 0; ii < 4; ii++) sc[(ty * 4 + ii) * 16 + tx] = dpart[ii];
  __syncthreads();
  if (tid < 64) {
    float sum = 0.f;
    for (int t = 0; t < 16; t++) sum += sc[tid * 16 + t];
    Dv[(size_t)bh * S_LEN + i0 + tid] = sum;
  }
}

// ---- bwd dq: per (bh, i-tile 64), loop j-tiles 32; writes bf16 GQ ----
__global__ __launch_bounds__(256) void bwd_q(const float* __restrict__ Q,
                                             const float* __restrict__ K,
                                             const float* __restrict__ V,
                                             const float* __restrict__ G,
                                             const float* __restrict__ mbuf,
                                             const float* __restrict__ lbuf,
                                             const float* __restrict__ Dv,
                                             __hip_bfloat16* __restrict__ GQ) {
  int it = 15 - blockIdx.x;
  int bh = blockIdx.y, b = bh / NH, h = bh % NH;
  int tid = threadIdx.x, ty = tid >> 4, tx = tid & 15;
  __shared__ float Qs[64][66];
  __shared__ float Gs[64][66];
  __shared__ float Ks[64][34];
  __shared__ float VdS[64][34];
  __shared__ float Krm[32][64];
  size_t base = (size_t)b * S_LEN * E_DIM + h * HD;
  int i0 = it * 64;

  #pragma unroll
  for (int t = 0; t < 4; t++) {
    int lin = tid + 256 * t;
    int r = lin >> 4, dc = (lin & 15) << 2;
    float4 v = *(const float4*)(Q + base + (size_t)(i0 + r) * E_DIM + dc);
    Qs[dc][r] = v.x; Qs[dc + 1][r] = v.y; Qs[dc + 2][r] = v.z; Qs[dc + 3][r] = v.w;
    float4 g = *(const float4*)(G + base + (size_t)(i0 + r) * E_DIM + dc);
    Gs[dc][r] = g.x; Gs[dc + 1][r] = g.y; Gs[dc + 2][r] = g.z; Gs[dc + 3][r] = g.w;
  }
  float mrow[4], lrow[4], drow[4];
  #pragma unroll
  for (int ii = 0; ii < 4; ii++) {
    size_t sid = (size_t)bh * S_LEN + i0 + ty * 4 + ii;
    mrow[ii] = mbuf[sid]; lrow[ii] = lbuf[sid]; drow[ii] = Dv[sid];
  }
  float dq[4][4] = {};

  int njt = 2 * it + 2;
  for (int jt = 0; jt < njt; jt++) {
    int j0 = jt * 32;
    __syncthreads();
    #pragma unroll
    for (int t = 0; t < 2; t++) {
      int lin = tid + 256 * t;
      int r = lin >> 4, dc = (lin & 15) << 2;
      float4 kv = *(const float4*)(K + base + (size_t)(j0 + r) * E_DIM + dc);
      Ks[dc][r] = kv.x; Ks[dc + 1][r] = kv.y; Ks[dc + 2][r] = kv.z; Ks[dc + 3][r] = kv.w;
      float4 vv = *(const float4*)(V + base + (size_t)(j0 + r) * E_DIM + dc);
      VdS[dc][r] = vv.x; VdS[dc + 1][r] = vv.y; VdS[dc + 2][r] = vv.z; VdS[dc + 3][r] = vv.w;
      *(float4*)&Krm[r][dc] = kv;
    }
    __syncthreads();
    float s[4][2] = {}, dp[4][2] = {};
    #pragma unroll 4
    for (int d = 0; d < 64; d++) {
      float2 qa = *(const float2*)&Qs[d][ty * 4];
      float2 qb = *(const float2*)&Qs[d][ty * 4 + 2];
      float2 ga = *(const float2*)&Gs[d][ty * 4];
      float2 gb = *(const float2*)&Gs[d][ty * 4 + 2];
      float2 kk = *(const float2*)&Ks[d][tx * 2];
      float2 vv = *(const float2*)&VdS[d][tx * 2];
      s[0][0] += qa.x * kk.x; s[0][1] += qa.x * kk.y;
      s[1][0] += qa.y * kk.x; s[1][1] += qa.y * kk.y;
      s[2][0] += qb.x * kk.x; s[2][1] += qb.x * kk.y;
      s[3][0] += qb.y * kk.x; s[3][1] += qb.y * kk.y;
      dp[0][0] += ga.x * vv.x; dp[0][1] += ga.x * vv.y;
      dp[1][0] += ga.y * vv.x; dp[1][1] += ga.y * vv.y;
      dp[2][0] += gb.x * vv.x; dp[2][1] += gb.x * vv.y;
      dp[3][0] += gb.y * vv.x; dp[3][1] += gb.y * vv.y;
    }
    __syncthreads();
    #pragma unroll
    for (int ii = 0; ii < 4; ii++) {
      int ig = i0 + ty * 4 + ii;
      #pragma unroll
      for (int jj = 0; jj < 2; jj++) {
        int jg = j0 + tx * 2 + jj;
        float dsv = 0.f;
        if (jg <= ig) {
          float P = __expf(s[ii][jj] * SC_C - mrow[ii]) * lrow[ii];
          dsv = P * (dp[ii][jj] - drow[ii]) * SC_C;
        }
        VdS[ty * 4 + ii][tx * 2 + jj] = dsv;
      }
    }
    __syncthreads();
    #pragma unroll 4
    for (int j = 0; j < 32; j++) {
      float4 k4 = *(const float4*)&Krm[j][tx * 4];
      float d0 = VdS[ty * 4 + 0][j], d1 = VdS[ty * 4 + 1][j];
      float d2 = VdS[ty * 4 + 2][j], d3 = VdS[ty * 4 + 3][j];
      dq[0][0] += d0 * k4.x; dq[0][1] += d0 * k4.y; dq[0][2] += d0 * k4.z; dq[0][3] += d0 * k4.w;
      dq[1][0] += d1 * k4.x; dq[1][1] += d1 * k4.y; dq[1][2] += d1 * k4.z; dq[1][3] += d1 * k4.w;
      dq[2][0] += d2 * k4.x; dq[2][1] += d2 * k4.y; dq[2][2] += d2 * k4.z; dq[2][3] += d2 * k4.w;
      dq[3][0] += d3 * k4.x; dq[3][1] += d3 * k4.y; dq[3][2] += d3 * k4.z; dq[3][3] += d3 * k4.w;
    }
  }
  #pragma unroll
  for (int ii = 0; ii < 4; ii++) {
    size_t gi = base + (size_t)(i0 + ty * 4 + ii) * E_DIM + tx * 4;
    GQ[gi + 0] = __float2bfloat16(dq[ii][0]);
    GQ[gi + 1] = __float2bfloat16(dq[ii][1]);
    GQ[gi + 2] = __float2bfloat16(dq[ii][2]);
    GQ[gi + 3] = __float2bfloat16(dq[ii][3]);
  }
}

// ---- bwd dk/dv: per (bh, j-tile 32), loop i-tiles 32; writes bf16 GK/GV ----
__global__ __launch_bounds__(256) void bwd_kv(const float* __restrict__ Q,
                                              const float* __restrict__ K,
                                              const float* __restrict__ V,
                                              const float* __restrict__ G,
                                              const float* __restrict__ mbuf,
                                              const float* __restrict__ lbuf,
                                              const float* __restrict__ Dv,
                                              __hip_bfloat16* __restrict__ GK,
                                              __hip_bfloat16* __restrict__ GV) {
  int jt = blockIdx.x;
  int bh = blockIdx.y, b = bh / NH, h = bh % NH;
  int tid = threadIdx.x, ty = tid >> 4, tx = tid & 15;
  __shared__ float Ks[64][34];
  __shared__ float Vs[64][34];
  __shared__ float Qs[64][34];
  __shared__ float Gs[64][34];
  __shared__ float Qrm[32][64];
  __shared__ float Grm[32][64];
  __shared__ float Ps[32][34];
  __shared__ float dSs[32][34];
  size_t base = (size_t)b * S_LEN * E_DIM + h * HD;
  int j0 = jt * 32;

  #pragma unroll
  for (int t = 0; t < 2; t++) {
    int lin = tid + 256 * t;
    int r = lin >> 4, dc = (lin & 15) << 2;
    float4 kv = *(const float4*)(K + base + (size_t)(j0 + r) * E_DIM + dc);
    Ks[dc][r] = kv.x; Ks[dc + 1][r] = kv.y; Ks[dc + 2][r] = kv.z; Ks[dc + 3][r] = kv.w;
    float4 vv = *(const float4*)(V + base + (size_t)(j0 + r) * E_DIM + dc);
    Vs[dc][r] = vv.x; Vs[dc + 1][r] = vv.y; Vs[dc + 2][r] = vv.z; Vs[dc + 3][r] = vv.w;
  }
  float dk[2][4] = {}, dv[2][4] = {};

  for (int i_t = jt; i_t < 32; i_t++) {
    int i0 = i_t * 32;
    __syncthreads();
    #pragma unroll
    for (int t = 0; t < 2; t++) {
      int lin = tid + 256 * t;
      int r = lin >> 4, dc = (lin & 15) << 2;
      float4 qv = *(const float4*)(Q + base + (size_t)(i0 + r) * E_DIM + dc);
      Qs[dc][r] = qv.x; Qs[dc + 1][r] = qv.y; Qs[dc + 2][r] = qv.z; Qs[dc + 3][r] = qv.w;
      float4 gv = *(const float4*)(G + base + (size_t)(i0 + r) * E_DIM + dc);
      Gs[dc][r] = gv.x; Gs[dc + 1][r] = gv.y; Gs[dc + 2][r] = gv.z; Gs[dc + 3][r] = gv.w;
      *(float4*)&Qrm[r][dc] = qv;
      *(float4*)&Grm[r][dc] = gv;
    }
    __syncthreads();
    float mr[2], lr[2], dr[2];
    #pragma unroll
    for (int il = 0; il < 2; il++) {
      size_t sid = (size_t)bh * S_LEN + i0 + ty * 2 + il;
      mr[il] = mbuf[sid]; lr[il] = lbuf[sid]; dr[il] = Dv[sid];
    }
    float s[2][2] = {}, dp[2][2] = {};
    #pragma unroll 4
    for (int d = 0; d < 64; d++) {
      float2 q = *(const float2*)&Qs[d][ty * 2];
      float2 g = *(const float2*)&Gs[d][ty * 2];
      float2 kk = *(const float2*)&Ks[d][tx * 2];
      float2 vv = *(const float2*)&Vs[d][tx * 2];
      s[0][0] += q.x * kk.x; s[0][1] += q.x * kk.y;
      s[1][0] += q.y * kk.x; s[1][1] += q.y * kk.y;
      dp[0][0] += g.x * vv.x; dp[0][1] += g.x * vv.y;
      dp[1][0] += g.y * vv.x; dp[1][1] += g.y * vv.y;
    }
    #pragma unroll
    for (int il = 0; il < 2; il++) {
      int ig = i0 + ty * 2 + il;
      #pragma unroll
      for (int jl = 0; jl < 2; jl++) {
        int jg = j0 + tx * 2 + jl;
        float P = 0.f, dsv = 0.f;
        if (ig >= jg) {
          P = __expf(s[il][jl] * SC_C - mr[il]) * lr[il];
          dsv = P * (dp[il][jl] - dr[il]) * SC_C;
        }
        Ps[ty * 2 + il][tx * 2 + jl] = P;
        dSs[ty * 2 + il][tx * 2 + jl] = dsv;
      }
    }
    __syncthreads();
    #pragma unroll 4
    for (int i_l = 0; i_l < 32; i_l++) {
      float2 p2 = *(const float2*)&Ps[i_l][ty * 2];
      float2 d2 = *(const float2*)&dSs[i_l][ty * 2];
      float4 g4 = *(const float4*)&Grm[i_l][tx * 4];
      float4 q4 = *(const float4*)&Qrm[i_l][tx * 4];
      dv[0][0] += p2.x * g4.x; dv[0][1] += p2.x * g4.y; dv[0][2] += p2.x * g4.z; dv[0][3] += p2.x * g4.w;
      dv[1][0] += p2.y * g4.x; dv[1][1] += p2.y * g4.y; dv[1][2] += p2.y * g4.z; dv[1][3] += p2.y * g4.w;
      dk[0][0] += d2.x * q4.x; dk[0][1] += d2.x * q4.y; dk[0][2] += d2.x * q4.z; dk[0][3] += d2.x * q4.w;
      dk[1][0] += d2.y * q4.x; dk[1][1] += d2.y * q4.y; dk[1][2] += d2.y * q4.z; dk[1][3] += d2.y * q4.w;
    }
  }
  #pragma unroll
  for (int jj = 0; jj < 2; jj++) {
    size_t gi = base + (size_t)(j0 + ty * 2 + jj) * E_DIM + tx * 4;
    GK[gi + 0] = __float2bfloat16(dk[jj][0]);
    GK[gi + 1] = __float2bfloat16(dk[jj][1]);
    GK[gi + 2] = __float2bfloat16(dk[jj][2]);
    GK[gi + 3] = __float2bfloat16(dk[jj][3]);
    GV[gi + 0] = __float2bfloat16(dv[jj][0]);
    GV[gi + 1] = __float2bfloat16(dv[jj][1]);
    GV[gi + 2] = __float2bfloat16(dv[jj][2]);
    GV[gi + 3] = __float2bfloat16(dv[jj][3]);
  }
}

// ---------------- launch ----------------
extern "C" void kernel_launch(void* const* d_in, const int* in_sizes, int n_in,
                              void* d_out, int out_size, void* d_ws, size_t ws_size,
                              hipStream_t stream) {
  const float* T1 = (const float*)d_in[0];   // fc1_x — stage-1 target
  const float* Wq = (const float*)d_in[1];
  const float* Wk = (const float*)d_in[2];
  const float* Wv = (const float*)d_in[3];
  const float* Wo = (const float*)d_in[4];

  const size_t M2 = 2097152;   // 2048*1024
  const size_t M1 = 1048576;   // 1024*1024
  float* w = (float*)d_ws;
  // fp32 buffers
  float* Xs = w;               // att_score (stage-2 target), fp32
  float* R  = Xs + M2;         // residual g (fp32); FIRST HALF doubles as X2b (bf16)
  float* Qb = R + M2;
  float* Kb = Qb + M2;
  float* Vb = Kb + M2;
  float* mS = Vb + M2;         // 32K
  float* lS = mS + 32768;
  float* DvS = lS + 32768;
  // bf16 region
  ushort_t* bws = (ushort_t*)(DvS + 32768);
  ushort_t* W0 = bws;               // weight slots, 1M bf16 each
  ushort_t* W1 = W0 + M1;
  ushort_t* W2 = W1 + M1;
  ushort_t* W3 = W2 + M1;
  ushort_t* W4 = W3 + M1;
  ushort_t* W5 = W4 + M1;
  ushort_t* GQb = W5 + M1;          // 2M bf16; stage-1 alias: Rb
  ushort_t* GKb = GQb + M2;         // 2M bf16; stage-1 alias: Xsb
  ushort_t* GVb = GKb + M2;         // 2M bf16
  ushort_t* Rb  = GQb;
  ushort_t* Xsb = GKb;
  ushort_t* X2b = (ushort_t*)R;     // bf16 mirror of X2; clobbered by fwd_o's R write
                                    // AFTER its qkv read, rewritten by accum — safe.
  float* X2 = (float*)d_out;        // stage-2 latent accumulates directly into d_out

  hipMemsetAsync(Xs, 0, M2 * sizeof(float), stream);
  hipMemsetAsync(Xsb, 0, M2 * sizeof(ushort_t), stream);
  hipMemsetAsync(X2, 0, M2 * sizeof(float), stream);
  hipMemsetAsync(X2b, 0, M2 * sizeof(ushort_t), stream);

  dim3 pgrid(16, 16);
  dim3 ggrid(8, 32);       // (N/128, M/64)
  dim3 ggrid3(8, 32, 3);

  // ---- stage 1: att_score = pc_infer(fc1_x, z -> z @ Wo^T) ----
  prep_w<<<pgrid, 256, 0, stream>>>(Wo, W0, W1);   // W0 = Wo bf16, W1 = Wo^T bf16
  for (int t = 0; t < 3; t++) {
    // Rb = bf16(T1 - Xs @ Wo^T):  A=Xsb, B(N,K form)=Wo straight
    gemm_mf<1, 1><<<ggrid, 256, 0, stream>>>(Xsb, nullptr, nullptr, W0, nullptr, nullptr,
                                             nullptr, nullptr, nullptr, T1, (__hip_bfloat16*)Rb, 0.f);
    // Xs += LR * Rb @ Wo:  B(N,K form)=Wo^T
    gemm_mf<2, 1><<<ggrid, 256, 0, stream>>>(Rb, nullptr, nullptr, W1, nullptr, nullptr,
                                             Xs, nullptr, nullptr, nullptr, (__hip_bfloat16*)Xsb, LR_C);
  }

  // stage-2 weights (reuses W0/W1 after stage-1 launches are queued)
  prep_w<<<pgrid, 256, 0, stream>>>(Wq, W0, W3);
  prep_w<<<pgrid, 256, 0, stream>>>(Wk, W1, W4);
  prep_w<<<pgrid, 256, 0, stream>>>(Wv, W2, W5);

  // ---- stage 2: x_qkv = pc_infer(att_score, causal MHA) ----
  dim3 agrid(16, BH_CNT), kvgrid(32, BH_CNT);
  for (int t = 0; t < 3; t++) {
    // Q/K/V = X2 @ W^T (one fused launch, z selects head)
    gemm_mf<0, 1><<<ggrid3, 256, 0, stream>>>(X2b, nullptr, nullptr, W0, W1, W2,
                                              Qb, Kb, Vb, nullptr, nullptr, 0.f);
    fwd_ml<<<agrid, 256, 0, stream>>>(Qb, Kb, mS, lS);
    fwd_o<<<agrid, 256, 0, stream>>>(Qb, Kb, Vb, Xs, mS, lS, R, DvS);
    bwd_q<<<agrid, 256, 0, stream>>>(Qb, Kb, Vb, R, mS, lS, DvS, (__hip_bfloat16*)GQb);
    bwd_kv<<<kvgrid, 256, 0, stream>>>(Qb, Kb, Vb, R, mS, lS, DvS,
                                       (__hip_bfloat16*)GKb, (__hip_bfloat16*)GVb);
    // X2 -= LR * (GQ@Wq + GK@Wk + GV@Wv)  — one fused 3-segment launch
    gemm_mf<2, 3><<<ggrid, 256, 0, stream>>>(GQb, GKb, GVb, W3, W4, W5,
                                             X2, nullptr, nullptr, nullptr, (__hip_bfloat16*)X2b, -LR_C);
  }
}

// Round 5
// 1376.482 us; speedup vs baseline: 14.5840x; 2.3190x over previous
//
#include <hip/hip_runtime.h>
#include <hip/hip_bf16.h>

// Problem constants (B=2, S=1024, E=1024, H=16, D=64)
#define S_LEN 1024
#define E_DIM 1024
#define NH 16
#define HD 64
#define M_ROWS 2048   // B*S
#define BH_CNT 32     // B*NH

static constexpr float LR_C = 0.01f;
static constexpr float SC_C = 0.125f;  // 1/sqrt(64)

typedef unsigned short ushort_t;
typedef __attribute__((ext_vector_type(8))) __bf16 bf16x8;
typedef __attribute__((ext_vector_type(4))) float f32x4;

static __device__ inline ushort_t f2bu(float f) {
  __hip_bfloat16 h = __float2bfloat16(f);
  return *(ushort_t*)&h;
}
static __device__ inline bf16x8 ldg8(const ushort_t* p) { return *(const bf16x8*)p; }

// ---------------- weight prep: bf16 cast + bf16 transpose, 64x64 tiles ----------------
__global__ __launch_bounds__(256) void prep_w(const float* __restrict__ W,
                                              ushort_t* __restrict__ Wb,
                                              ushort_t* __restrict__ WTb) {
  __shared__ float ts[64][65];
  int bx = blockIdx.x * 64, by = blockIdx.y * 64;
  int t = threadIdx.x;
  int rr = t >> 6, cc = t & 63;
  #pragma unroll
  for (int p = 0; p < 16; p++) {
    int r = p * 4 + rr;
    float v = W[(size_t)(by + r) * E_DIM + bx + cc];
    ts[r][cc] = v;
    Wb[(size_t)(by + r) * E_DIM + bx + cc] = f2bu(v);
  }
  __syncthreads();
  #pragma unroll
  for (int p = 0; p < 16; p++) {
    int r = p * 4 + rr;
    WTb[(size_t)(bx + r) * E_DIM + by + cc] = f2bu(ts[cc][r]);
  }
}

// ---------------- per-head transpose: X[token][E] (head h cols) -> Xt[bh][64][S] ----------------
__global__ __launch_bounds__(256) void tr_head(const ushort_t* __restrict__ s0,
                                               const ushort_t* __restrict__ s1,
                                               const ushort_t* __restrict__ s2,
                                               ushort_t* __restrict__ d0,
                                               ushort_t* __restrict__ d1,
                                               ushort_t* __restrict__ d2) {
  int z = blockIdx.z;
  const ushort_t* src = (z == 0) ? s0 : (z == 1) ? s1 : s2;
  ushort_t* dst = (z == 0) ? d0 : (z == 1) ? d1 : d2;
  int t0 = blockIdx.x * 64;
  int bh = blockIdx.y, b = bh >> 4, h = bh & 15;
  __shared__ ushort_t L[64][72];
  int tid = threadIdx.x;
  #pragma unroll
  for (int p = 0; p < 2; p++) {
    int lin = tid + 256 * p;
    int r = lin >> 3, c = (lin & 7) * 8;
    *(uint4*)&L[r][c] = *(const uint4*)(src + (size_t)(b * S_LEN + t0 + r) * E_DIM + h * HD + c);
  }
  __syncthreads();
  #pragma unroll
  for (int p = 0; p < 2; p++) {
    int lin = tid + 256 * p;
    int d = lin & 63, tc = (lin >> 6) * 8;
    ushort_t tmp[8];
    #pragma unroll
    for (int u = 0; u < 8; u++) tmp[u] = L[tc + u][d];
    *(uint4*)(dst + (size_t)(bh * HD + d) * S_LEN + t0 + tc) = *(uint4*)tmp;
  }
}

// ---------------- bf16 MFMA GEMM: C[M=2048,N=1024] = A[M,K=1024] * B[N,K]^T ----------------
// MODE 0: Cb_z = bf16(acc), z selects (B,Cb) of 3         [QKV projection, bf16 out]
// MODE 1: Cb0 = bf16(T - acc)                             [stage-1 residual]
// MODE 2: Cf += alpha*acc (fp32) and Cb0 = bf16(Cf), NSEG K-segments [PC update]
template <int MODE, int NSEG>
__global__ __launch_bounds__(256) void gemm_mf(
    const ushort_t* __restrict__ A0, const ushort_t* __restrict__ A1, const ushort_t* __restrict__ A2,
    const ushort_t* __restrict__ B0, const ushort_t* __restrict__ B1, const ushort_t* __restrict__ B2,
    float* __restrict__ Cf, const float* __restrict__ T,
    ushort_t* __restrict__ Cb0, ushort_t* __restrict__ Cb1, ushort_t* __restrict__ Cb2,
    float alpha) {
  const int K = 1024;
  __shared__ __bf16 As[64][40];
  __shared__ __bf16 Bs[128][40];
  int tid = threadIdx.x;
  int m0 = blockIdx.y * 64, n0 = blockIdx.x * 128;

  const ushort_t* Bsel = B0;
  ushort_t* Cbz = Cb0;
  if (MODE == 0) {
    int z = blockIdx.z;
    Bsel = (z == 0) ? B0 : (z == 1) ? B1 : B2;
    Cbz = (z == 0) ? Cb0 : (z == 1) ? Cb1 : Cb2;
  }

  int lane = tid & 63, wave = tid >> 6;
  int wrow = wave >> 1, wcol = wave & 1;
  int fr = lane & 15, q = lane >> 4;

  f32x4 acc[2][4] = {};

  int ar = tid >> 2, ac = (tid & 3) * 8;
  #pragma unroll 1
  for (int seg = 0; seg < NSEG; seg++) {
    const ushort_t* Aseg = (seg == 0) ? A0 : (seg == 1) ? A1 : A2;
    const ushort_t* Bseg = (MODE == 0) ? Bsel : ((seg == 0) ? B0 : (seg == 1) ? B1 : B2);
    const ushort_t* Ag = Aseg + (size_t)(m0 + ar) * K + ac;
    const ushort_t* Bg0 = Bseg + (size_t)(n0 + ar) * K + ac;
    const ushort_t* Bg1 = Bseg + (size_t)(n0 + 64 + ar) * K + ac;
    for (int k0 = 0; k0 < K; k0 += 32) {
      uint4 av = *(const uint4*)(Ag + k0);
      uint4 bv0 = *(const uint4*)(Bg0 + k0);
      uint4 bv1 = *(const uint4*)(Bg1 + k0);
      __syncthreads();
      *(uint4*)&As[ar][ac] = av;
      *(uint4*)&Bs[ar][ac] = bv0;
      *(uint4*)&Bs[64 + ar][ac] = bv1;
      __syncthreads();
      bf16x8 a0 = *(const bf16x8*)&As[wrow * 32 + fr][q * 8];
      bf16x8 a1 = *(const bf16x8*)&As[wrow * 32 + 16 + fr][q * 8];
      bf16x8 b0 = *(const bf16x8*)&Bs[wcol * 64 + fr][q * 8];
      bf16x8 b1 = *(const bf16x8*)&Bs[wcol * 64 + 16 + fr][q * 8];
      bf16x8 b2 = *(const bf16x8*)&Bs[wcol * 64 + 32 + fr][q * 8];
      bf16x8 b3 = *(const bf16x8*)&Bs[wcol * 64 + 48 + fr][q * 8];
      acc[0][0] = __builtin_amdgcn_mfma_f32_16x16x32_bf16(a0, b0, acc[0][0], 0, 0, 0);
      acc[0][1] = __builtin_amdgcn_mfma_f32_16x16x32_bf16(a0, b1, acc[0][1], 0, 0, 0);
      acc[0][2] = __builtin_amdgcn_mfma_f32_16x16x32_bf16(a0, b2, acc[0][2], 0, 0, 0);
      acc[0][3] = __builtin_amdgcn_mfma_f32_16x16x32_bf16(a0, b3, acc[0][3], 0, 0, 0);
      acc[1][0] = __builtin_amdgcn_mfma_f32_16x16x32_bf16(a1, b0, acc[1][0], 0, 0, 0);
      acc[1][1] = __builtin_amdgcn_mfma_f32_16x16x32_bf16(a1, b1, acc[1][1], 0, 0, 0);
      acc[1][2] = __builtin_amdgcn_mfma_f32_16x16x32_bf16(a1, b2, acc[1][2], 0, 0, 0);
      acc[1][3] = __builtin_amdgcn_mfma_f32_16x16x32_bf16(a1, b3, acc[1][3], 0, 0, 0);
    }
  }

  #pragma unroll
  for (int mi = 0; mi < 2; mi++)
    #pragma unroll
    for (int ni = 0; ni < 4; ni++) {
      int col = n0 + wcol * 64 + ni * 16 + fr;
      int row0 = m0 + wrow * 32 + mi * 16 + q * 4;
      #pragma unroll
      for (int r = 0; r < 4; r++) {
        size_t idx = (size_t)(row0 + r) * E_DIM + col;
        float v = acc[mi][ni][r];
        if (MODE == 0) {
          Cbz[idx] = f2bu(v);
        } else if (MODE == 1) {
          Cb0[idx] = f2bu(T[idx] - v);
        } else {
          float nv = Cf[idx] + alpha * v;
          Cf[idx] = nv;
          Cb0[idx] = f2bu(nv);
        }
      }
    }
}

// ====================== MFMA attention ======================
// All operands bf16 in global: X[token][1024] (head cols h*64..), Xt[bh][64][S].
// MFMA 16x16x32: A[m=lane&15][k=q*8+j], B[n=lane&15][k=q*8+j], C: col=lane&15,row=q*4+reg.
// i-tile 64 per block (4 waves = 4 row-bands of 16); j/i inner tiles 64.

// ---- fwd pass 1: per-row m, 1/l via MFMA S recompute + online softmax ----
__global__ __launch_bounds__(256) void fwd_ml(const ushort_t* __restrict__ Qg,
                                              const ushort_t* __restrict__ Kg,
                                              float* __restrict__ mbuf,
                                              float* __restrict__ lbuf) {
  int it = 15 - blockIdx.x;
  int bh = blockIdx.y, b = bh >> 4, h = bh & 15;
  int tid = threadIdx.x, lane = tid & 63, wv = tid >> 6;
  int fr = lane & 15, q = lane >> 4;
  int i0 = it * 64, band = wv * 16;
  __shared__ float redm[64][17];
  __shared__ float redl[64][17];

  const ushort_t* Qrow = Qg + (size_t)(b * S_LEN + i0 + band + fr) * E_DIM + h * HD;
  bf16x8 aq0 = ldg8(Qrow + q * 8);
  bf16x8 aq1 = ldg8(Qrow + 32 + q * 8);

  float mr[4], lr[4];
  #pragma unroll
  for (int r = 0; r < 4; r++) { mr[r] = -1e30f; lr[r] = 0.f; }

  for (int jt = 0; jt <= it; jt++) {
    int j0 = jt * 64;
    f32x4 sA[4];
    #pragma unroll
    for (int nc = 0; nc < 4; nc++) {
      const ushort_t* Krow = Kg + (size_t)(b * S_LEN + j0 + nc * 16 + fr) * E_DIM + h * HD;
      bf16x8 bk0 = ldg8(Krow + q * 8);
      bf16x8 bk1 = ldg8(Krow + 32 + q * 8);
      f32x4 z = {};
      z = __builtin_amdgcn_mfma_f32_16x16x32_bf16(aq0, bk0, z, 0, 0, 0);
      sA[nc] = __builtin_amdgcn_mfma_f32_16x16x32_bf16(aq1, bk1, z, 0, 0, 0);
    }
    #pragma unroll
    for (int nc = 0; nc < 4; nc++)
      #pragma unroll
      for (int r = 0; r < 4; r++) {
        int row = i0 + band + q * 4 + r;
        int col = j0 + nc * 16 + fr;
        if (col <= row) {
          float sv = sA[nc][r] * SC_C;
          float mn = fmaxf(mr[r], sv);
          lr[r] = lr[r] * __expf(mr[r] - mn) + __expf(sv - mn);
          mr[r] = mn;
        }
      }
  }
  #pragma unroll
  for (int r = 0; r < 4; r++) {
    redm[band + q * 4 + r][fr] = mr[r];
    redl[band + q * 4 + r][fr] = lr[r];
  }
  __syncthreads();
  if (tid < 64) {
    float m = -1e30f;
    #pragma unroll
    for (int k = 0; k < 16; k++) m = fmaxf(m, redm[tid][k]);
    float l = 0.f;
    #pragma unroll
    for (int k = 0; k < 16; k++) l += redl[tid][k] * __expf(redm[tid][k] - m);
    size_t sid = (size_t)bh * S_LEN + i0 + tid;
    mbuf[sid] = m;
    lbuf[sid] = 1.0f / l;
  }
}

// ---- fwd pass 2: O = P V (MFMA); fused g = O - Xs (bf16 out) and Dv = rowdot(g,O) ----
__global__ __launch_bounds__(256) void fwd_o(const ushort_t* __restrict__ Qg,
                                             const ushort_t* __restrict__ Kg,
                                             const ushort_t* __restrict__ Vt,
                                             const float* __restrict__ Xs,
                                             const float* __restrict__ mbuf,
                                             const float* __restrict__ lbuf,
                                             ushort_t* __restrict__ Gb,
                                             float* __restrict__ Dv) {
  int it = 15 - blockIdx.x;
  int bh = blockIdx.y, b = bh >> 4, h = bh & 15;
  int tid = threadIdx.x, lane = tid & 63, wv = tid >> 6;
  int fr = lane & 15, q = lane >> 4;
  int i0 = it * 64, band = wv * 16;
  __shared__ ushort_t Ps[64][72];
  __shared__ float red[64][17];

  const ushort_t* Qrow = Qg + (size_t)(b * S_LEN + i0 + band + fr) * E_DIM + h * HD;
  bf16x8 aq0 = ldg8(Qrow + q * 8);
  bf16x8 aq1 = ldg8(Qrow + 32 + q * 8);

  float mrow[4], linv[4];
  #pragma unroll
  for (int r = 0; r < 4; r++) {
    size_t sid = (size_t)bh * S_LEN + i0 + band + q * 4 + r;
    mrow[r] = mbuf[sid]; linv[r] = lbuf[sid];
  }
  f32x4 oacc[4] = {};

  for (int jt = 0; jt <= it; jt++) {
    int j0 = jt * 64;
    f32x4 sA[4];
    #pragma unroll
    for (int nc = 0; nc < 4; nc++) {
      const ushort_t* Krow = Kg + (size_t)(b * S_LEN + j0 + nc * 16 + fr) * E_DIM + h * HD;
      bf16x8 bk0 = ldg8(Krow + q * 8);
      bf16x8 bk1 = ldg8(Krow + 32 + q * 8);
      f32x4 z = {};
      z = __builtin_amdgcn_mfma_f32_16x16x32_bf16(aq0, bk0, z, 0, 0, 0);
      sA[nc] = __builtin_amdgcn_mfma_f32_16x16x32_bf16(aq1, bk1, z, 0, 0, 0);
    }
    #pragma unroll
    for (int nc = 0; nc < 4; nc++)
      #pragma unroll
      for (int r = 0; r < 4; r++) {
        int row = i0 + band + q * 4 + r;
        int col = j0 + nc * 16 + fr;
        float P = 0.f;
        if (col <= row) P = __expf(sA[nc][r] * SC_C - mrow[r]) * linv[r];
        Ps[band + q * 4 + r][nc * 16 + fr] = f2bu(P);  // wave-private rows: no barrier
      }
    bf16x8 ap0 = *(const bf16x8*)&Ps[band + fr][q * 8];
    bf16x8 ap1 = *(const bf16x8*)&Ps[band + fr][32 + q * 8];
    #pragma unroll
    for (int nc = 0; nc < 4; nc++) {
      const ushort_t* Vtr = Vt + (size_t)(bh * HD + nc * 16 + fr) * S_LEN + j0;
      bf16x8 bv0 = ldg8(Vtr + q * 8);
      bf16x8 bv1 = ldg8(Vtr + 32 + q * 8);
      oacc[nc] = __builtin_amdgcn_mfma_f32_16x16x32_bf16(ap0, bv0, oacc[nc], 0, 0, 0);
      oacc[nc] = __builtin_amdgcn_mfma_f32_16x16x32_bf16(ap1, bv1, oacc[nc], 0, 0, 0);
    }
  }
  // epilogue: g = O - Xs (bf16), Dv partials
  float dpart[4] = {};
  #pragma unroll
  for (int nc = 0; nc < 4; nc++)
    #pragma unroll
    for (int r = 0; r < 4; r++) {
      int row = i0 + band + q * 4 + r;
      int d = nc * 16 + fr;
      size_t gi = (size_t)(b * S_LEN + row) * E_DIM + h * HD + d;
      float o = oacc[nc][r];
      float g = o - Xs[gi];
      Gb[gi] = f2bu(g);
      dpart[r] += g * o;
    }
  #pragma unroll
  for (int r = 0; r < 4; r++) red[band + q * 4 + r][fr] = dpart[r];
  __syncthreads();
  if (tid < 64) {
    float sum = 0.f;
    #pragma unroll
    for (int k = 0; k < 16; k++) sum += red[tid][k];
    Dv[(size_t)bh * S_LEN + i0 + tid] = sum;
  }
}

// ---- bwd dq: S=QK^T, dP=GV^T, dS -> LDS, dq = dS*K (via Kt) ----
__global__ __launch_bounds__(256) void bwd_q(const ushort_t* __restrict__ Qg,
                                             const ushort_t* __restrict__ Kg,
                                             const ushort_t* __restrict__ Vg,
                                             const ushort_t* __restrict__ Gg,
                                             const ushort_t* __restrict__ Kt,
                                             const float* __restrict__ mbuf,
                                             const float* __restrict__ lbuf,
                                             const float* __restrict__ Dv,
                                             ushort_t* __restrict__ GQ) {
  int it = 15 - blockIdx.x;
  int bh = blockIdx.y, b = bh >> 4, h = bh & 15;
  int tid = threadIdx.x, lane = tid & 63, wv = tid >> 6;
  int fr = lane & 15, q = lane >> 4;
  int i0 = it * 64, band = wv * 16;
  __shared__ ushort_t dSs[64][72];

  const ushort_t* Qrow = Qg + (size_t)(b * S_LEN + i0 + band + fr) * E_DIM + h * HD;
  const ushort_t* Grow = Gg + (size_t)(b * S_LEN + i0 + band + fr) * E_DIM + h * HD;
  bf16x8 aq0 = ldg8(Qrow + q * 8), aq1 = ldg8(Qrow + 32 + q * 8);
  bf16x8 ag0 = ldg8(Grow + q * 8), ag1 = ldg8(Grow + 32 + q * 8);

  float mrow[4], linv[4], Dr[4];
  #pragma unroll
  for (int r = 0; r < 4; r++) {
    size_t sid = (size_t)bh * S_LEN + i0 + band + q * 4 + r;
    mrow[r] = mbuf[sid]; linv[r] = lbuf[sid]; Dr[r] = Dv[sid];
  }
  f32x4 dqacc[4] = {};

  for (int jt = 0; jt <= it; jt++) {
    int j0 = jt * 64;
    f32x4 sA[4], dpA[4];
    #pragma unroll
    for (int nc = 0; nc < 4; nc++) {
      const ushort_t* Krow = Kg + (size_t)(b * S_LEN + j0 + nc * 16 + fr) * E_DIM + h * HD;
      const ushort_t* Vrow = Vg + (size_t)(b * S_LEN + j0 + nc * 16 + fr) * E_DIM + h * HD;
      bf16x8 bk0 = ldg8(Krow + q * 8), bk1 = ldg8(Krow + 32 + q * 8);
      bf16x8 bv0 = ldg8(Vrow + q * 8), bv1 = ldg8(Vrow + 32 + q * 8);
      f32x4 z = {};
      z = __builtin_amdgcn_mfma_f32_16x16x32_bf16(aq0, bk0, z, 0, 0, 0);
      sA[nc] = __builtin_amdgcn_mfma_f32_16x16x32_bf16(aq1, bk1, z, 0, 0, 0);
      f32x4 z2 = {};
      z2 = __builtin_amdgcn_mfma_f32_16x16x32_bf16(ag0, bv0, z2, 0, 0, 0);
      dpA[nc] = __builtin_amdgcn_mfma_f32_16x16x32_bf16(ag1, bv1, z2, 0, 0, 0);
    }
    #pragma unroll
    for (int nc = 0; nc < 4; nc++)
      #pragma unroll
      for (int r = 0; r < 4; r++) {
        int row = i0 + band + q * 4 + r;
        int col = j0 + nc * 16 + fr;
        float ds = 0.f;
        if (col <= row) {
          float P = __expf(sA[nc][r] * SC_C - mrow[r]) * linv[r];
          ds = P * (dpA[nc][r] - Dr[r]) * SC_C;
        }
        dSs[band + q * 4 + r][nc * 16 + fr] = f2bu(ds);  // wave-private
      }
    bf16x8 ad0 = *(const bf16x8*)&dSs[band + fr][q * 8];
    bf16x8 ad1 = *(const bf16x8*)&dSs[band + fr][32 + q * 8];
    #pragma unroll
    for (int nc = 0; nc < 4; nc++) {
      const ushort_t* Ktr = Kt + (size_t)(bh * HD + nc * 16 + fr) * S_LEN + j0;
      bf16x8 bt0 = ldg8(Ktr + q * 8);
      bf16x8 bt1 = ldg8(Ktr + 32 + q * 8);
      dqacc[nc] = __builtin_amdgcn_mfma_f32_16x16x32_bf16(ad0, bt0, dqacc[nc], 0, 0, 0);
      dqacc[nc] = __builtin_amdgcn_mfma_f32_16x16x32_bf16(ad1, bt1, dqacc[nc], 0, 0, 0);
    }
  }
  #pragma unroll
  for (int nc = 0; nc < 4; nc++)
    #pragma unroll
    for (int r = 0; r < 4; r++) {
      int row = i0 + band + q * 4 + r;
      size_t gi = (size_t)(b * S_LEN + row) * E_DIM + h * HD + nc * 16 + fr;
      GQ[gi] = f2bu(dqacc[nc][r]);
    }
}

// ---- bwd dk/dv: rows=j. ST=K*Q^T, dPT=V*G^T, PT/dST -> LDS, dv=PT*G (Gt), dk=dST*Q (Qt) ----
__global__ __launch_bounds__(256) void bwd_kv(const ushort_t* __restrict__ Qg,
                                              const ushort_t* __restrict__ Kg,
                                              const ushort_t* __restrict__ Vg,
                                              const ushort_t* __restrict__ Gg,
                                              const ushort_t* __restrict__ Qt,
                                              const ushort_t* __restrict__ Gt,
                                              const float* __restrict__ mbuf,
                                              const float* __restrict__ lbuf,
                                              const float* __restrict__ Dv,
                                              ushort_t* __restrict__ GK,
                                              ushort_t* __restrict__ GV) {
  int jt = blockIdx.x;  // jt=0 heaviest, dispatched first
  int bh = blockIdx.y, b = bh >> 4, h = bh & 15;
  int tid = threadIdx.x, lane = tid & 63, wv = tid >> 6;
  int fr = lane & 15, q = lane >> 4;
  int j0 = jt * 64, band = wv * 16;
  __shared__ ushort_t PT[64][72];
  __shared__ ushort_t dST[64][72];

  const ushort_t* Krow = Kg + (size_t)(b * S_LEN + j0 + band + fr) * E_DIM + h * HD;
  const ushort_t* Vrow = Vg + (size_t)(b * S_LEN + j0 + band + fr) * E_DIM + h * HD;
  bf16x8 ak0 = ldg8(Krow + q * 8), ak1 = ldg8(Krow + 32 + q * 8);
  bf16x8 av0 = ldg8(Vrow + q * 8), av1 = ldg8(Vrow + 32 + q * 8);

  f32x4 dkacc[4] = {}, dvacc[4] = {};

  for (int i_t = jt; i_t < 16; i_t++) {
    int i0 = i_t * 64;
    float mc[4], lc[4], Dc[4];
    #pragma unroll
    for (int nc = 0; nc < 4; nc++) {
      size_t sid = (size_t)bh * S_LEN + i0 + nc * 16 + fr;
      mc[nc] = mbuf[sid]; lc[nc] = lbuf[sid]; Dc[nc] = Dv[sid];
    }
    f32x4 stA[4], dptA[4];
    #pragma unroll
    for (int nc = 0; nc < 4; nc++) {
      const ushort_t* Qrow = Qg + (size_t)(b * S_LEN + i0 + nc * 16 + fr) * E_DIM + h * HD;
      const ushort_t* Grow = Gg + (size_t)(b * S_LEN + i0 + nc * 16 + fr) * E_DIM + h * HD;
      bf16x8 bq0 = ldg8(Qrow + q * 8), bq1 = ldg8(Qrow + 32 + q * 8);
      bf16x8 bg0 = ldg8(Grow + q * 8), bg1 = ldg8(Grow + 32 + q * 8);
      f32x4 z = {};
      z = __builtin_amdgcn_mfma_f32_16x16x32_bf16(ak0, bq0, z, 0, 0, 0);
      stA[nc] = __builtin_amdgcn_mfma_f32_16x16x32_bf16(ak1, bq1, z, 0, 0, 0);
      f32x4 z2 = {};
      z2 = __builtin_amdgcn_mfma_f32_16x16x32_bf16(av0, bg0, z2, 0, 0, 0);
      dptA[nc] = __builtin_amdgcn_mfma_f32_16x16x32_bf16(av1, bg1, z2, 0, 0, 0);
    }
    #pragma unroll
    for (int nc = 0; nc < 4; nc++)
      #pragma unroll
      for (int r = 0; r < 4; r++) {
        int jrow = j0 + band + q * 4 + r;
        int icol = i0 + nc * 16 + fr;
        float P = 0.f, ds = 0.f;
        if (icol >= jrow) {
          P = __expf(stA[nc][r] * SC_C - mc[nc]) * lc[nc];
          ds = P * (dptA[nc][r] - Dc[nc]) * SC_C;
        }
        PT[band + q * 4 + r][nc * 16 + fr] = f2bu(P);   // wave-private
        dST[band + q * 4 + r][nc * 16 + fr] = f2bu(ds);
      }
    bf16x8 ap0 = *(const bf16x8*)&PT[band + fr][q * 8];
    bf16x8 ap1 = *(const bf16x8*)&PT[band + fr][32 + q * 8];
    bf16x8 ad0 = *(const bf16x8*)&dST[band + fr][q * 8];
    bf16x8 ad1 = *(const bf16x8*)&dST[band + fr][32 + q * 8];
    #pragma unroll
    for (int nc = 0; nc < 4; nc++) {
      const ushort_t* Gtr = Gt + (size_t)(bh * HD + nc * 16 + fr) * S_LEN + i0;
      const ushort_t* Qtr = Qt + (size_t)(bh * HD + nc * 16 + fr) * S_LEN + i0;
      bf16x8 bg0 = ldg8(Gtr + q * 8), bg1 = ldg8(Gtr + 32 + q * 8);
      bf16x8 bq0 = ldg8(Qtr + q * 8), bq1 = ldg8(Qtr + 32 + q * 8);
      dvacc[nc] = __builtin_amdgcn_mfma_f32_16x16x32_bf16(ap0, bg0, dvacc[nc], 0, 0, 0);
      dvacc[nc] = __builtin_amdgcn_mfma_f32_16x16x32_bf16(ap1, bg1, dvacc[nc], 0, 0, 0);
      dkacc[nc] = __builtin_amdgcn_mfma_f32_16x16x32_bf16(ad0, bq0, dkacc[nc], 0, 0, 0);
      dkacc[nc] = __builtin_amdgcn_mfma_f32_16x16x32_bf16(ad1, bq1, dkacc[nc], 0, 0, 0);
    }
  }
  #pragma unroll
  for (int nc = 0; nc < 4; nc++)
    #pragma unroll
    for (int r = 0; r < 4; r++) {
      int jrow = j0 + band + q * 4 + r;
      size_t gi = (size_t)(b * S_LEN + jrow) * E_DIM + h * HD + nc * 16 + fr;
      GK[gi] = f2bu(dkacc[nc][r]);
      GV[gi] = f2bu(dvacc[nc][r]);
    }
}

// ---------------- launch ----------------
extern "C" void kernel_launch(void* const* d_in, const int* in_sizes, int n_in,
                              void* d_out, int out_size, void* d_ws, size_t ws_size,
                              hipStream_t stream) {
  const float* T1 = (const float*)d_in[0];
  const float* Wq = (const float*)d_in[1];
  const float* Wk = (const float*)d_in[2];
  const float* Wv = (const float*)d_in[3];
  const float* Wo = (const float*)d_in[4];

  const size_t M2 = 2097152;   // 2048*1024
  const size_t M1 = 1048576;
  float* w = (float*)d_ws;
  float* Xs = w;                       // 8 MB fp32 target
  float* mS = Xs + M2;                 // 64K f32
  float* lS = mS + 65536;
  float* DvS = lS + 65536;
  ushort_t* u = (ushort_t*)(DvS + 65536);
  ushort_t* W0 = u;          ushort_t* W1 = W0 + M1;  ushort_t* W2 = W1 + M1;
  ushort_t* W3 = W2 + M1;    ushort_t* W4 = W3 + M1;  ushort_t* W5 = W4 + M1;
  ushort_t* Qb = W5 + M1;    ushort_t* Kb = Qb + M2;  ushort_t* Vb = Kb + M2;
  ushort_t* Qt = Vb + M2;    ushort_t* Kt = Qt + M2;  ushort_t* Vt = Kt + M2;
  ushort_t* Gt = Vt + M2;
  ushort_t* Gb = Gt + M2;
  ushort_t* GQb = Gb + M2;   ushort_t* GKb = GQb + M2; ushort_t* GVb = GKb + M2;
  ushort_t* X2b = GVb + M2;
  ushort_t* Rb = GQb;        // stage-1 aliases
  ushort_t* Xsb = GKb;
  float* X2 = (float*)d_out;

  hipMemsetAsync(Xs, 0, M2 * sizeof(float), stream);
  hipMemsetAsync(Xsb, 0, M2 * sizeof(ushort_t), stream);
  hipMemsetAsync(X2, 0, M2 * sizeof(float), stream);
  hipMemsetAsync(X2b, 0, M2 * sizeof(ushort_t), stream);

  dim3 pgrid(16, 16);
  dim3 ggrid(8, 32);
  dim3 ggrid3(8, 32, 3);
  dim3 agrid(16, BH_CNT);
  dim3 tgrid3(16, BH_CNT, 3);
  dim3 tgrid1(16, BH_CNT, 1);

  // ---- stage 1 ----
  prep_w<<<pgrid, 256, 0, stream>>>(Wo, W0, W1);
  for (int t = 0; t < 3; t++) {
    gemm_mf<1, 1><<<ggrid, 256, 0, stream>>>(Xsb, nullptr, nullptr, W0, nullptr, nullptr,
                                             nullptr, T1, Rb, nullptr, nullptr, 0.f);
    gemm_mf<2, 1><<<ggrid, 256, 0, stream>>>(Rb, nullptr, nullptr, W1, nullptr, nullptr,
                                             Xs, nullptr, Xsb, nullptr, nullptr, LR_C);
  }
  prep_w<<<pgrid, 256, 0, stream>>>(Wq, W0, W3);
  prep_w<<<pgrid, 256, 0, stream>>>(Wk, W1, W4);
  prep_w<<<pgrid, 256, 0, stream>>>(Wv, W2, W5);

  // ---- stage 2 ----
  for (int t = 0; t < 3; t++) {
    gemm_mf<0, 1><<<ggrid3, 256, 0, stream>>>(X2b, nullptr, nullptr, W0, W1, W2,
                                              nullptr, nullptr, Qb, Kb, Vb, 0.f);
    tr_head<<<tgrid3, 256, 0, stream>>>(Qb, Kb, Vb, Qt, Kt, Vt);
    fwd_ml<<<agrid, 256, 0, stream>>>(Qb, Kb, mS, lS);
    fwd_o<<<agrid, 256, 0, stream>>>(Qb, Kb, Vt, Xs, mS, lS, Gb, DvS);
    tr_head<<<tgrid1, 256, 0, stream>>>(Gb, nullptr, nullptr, Gt, nullptr, nullptr);
    bwd_q<<<agrid, 256, 0, stream>>>(Qb, Kb, Vb, Gb, Kt, mS, lS, DvS, GQb);
    bwd_kv<<<agrid, 256, 0, stream>>>(Qb, Kb, Vb, Gb, Qt, Gt, mS, lS, DvS, GKb, GVb);
    gemm_mf<2, 3><<<ggrid, 256, 0, stream>>>(GQb, GKb, GVb, W3, W4, W5,
                                             X2, nullptr, X2b, nullptr, nullptr, -LR_C);
  }
}

// Round 6
// 901.148 us; speedup vs baseline: 22.2767x; 1.5275x over previous
//
#include <hip/hip_runtime.h>
#include <hip/hip_bf16.h>

// Problem constants (B=2, S=1024, E=1024, H=16, D=64)
#define S_LEN 1024
#define E_DIM 1024
#define NH 16
#define HD 64
#define M_ROWS 2048   // B*S
#define BH_CNT 32     // B*NH

static constexpr float LR_C = 0.01f;
static constexpr float SC_C = 0.125f;  // 1/sqrt(64)

typedef unsigned short ushort_t;
typedef __attribute__((ext_vector_type(8))) __bf16 bf16x8;
typedef __attribute__((ext_vector_type(4))) float f32x4;

static __device__ inline ushort_t f2bu(float f) {
  __hip_bfloat16 h = __float2bfloat16(f);
  return *(ushort_t*)&h;
}
static __device__ inline bf16x8 ldg8(const ushort_t* p) { return *(const bf16x8*)p; }

// ---------------- weight prep: bf16 cast + bf16 transpose, 64x64 tiles ----------------
__global__ __launch_bounds__(256) void prep_w(const float* __restrict__ W,
                                              ushort_t* __restrict__ Wb,
                                              ushort_t* __restrict__ WTb) {
  __shared__ float ts[64][65];
  int bx = blockIdx.x * 64, by = blockIdx.y * 64;
  int t = threadIdx.x;
  int rr = t >> 6, cc = t & 63;
  #pragma unroll
  for (int p = 0; p < 16; p++) {
    int r = p * 4 + rr;
    float v = W[(size_t)(by + r) * E_DIM + bx + cc];
    ts[r][cc] = v;
    Wb[(size_t)(by + r) * E_DIM + bx + cc] = f2bu(v);
  }
  __syncthreads();
  #pragma unroll
  for (int p = 0; p < 16; p++) {
    int r = p * 4 + rr;
    WTb[(size_t)(bx + r) * E_DIM + by + cc] = f2bu(ts[cc][r]);
  }
}

// ---------------- per-head transpose: X[token][E] (head h cols) -> Xt[bh][64][S] ----------------
__global__ __launch_bounds__(256) void tr_head(const ushort_t* __restrict__ s0,
                                               const ushort_t* __restrict__ s1,
                                               const ushort_t* __restrict__ s2,
                                               ushort_t* __restrict__ d0,
                                               ushort_t* __restrict__ d1,
                                               ushort_t* __restrict__ d2) {
  int z = blockIdx.z;
  const ushort_t* src = (z == 0) ? s0 : (z == 1) ? s1 : s2;
  ushort_t* dst = (z == 0) ? d0 : (z == 1) ? d1 : d2;
  int t0 = blockIdx.x * 64;
  int bh = blockIdx.y, b = bh >> 4, h = bh & 15;
  __shared__ ushort_t L[64][72];
  int tid = threadIdx.x;
  #pragma unroll
  for (int p = 0; p < 2; p++) {
    int lin = tid + 256 * p;
    int r = lin >> 3, c = (lin & 7) * 8;
    *(uint4*)&L[r][c] = *(const uint4*)(src + (size_t)(b * S_LEN + t0 + r) * E_DIM + h * HD + c);
  }
  __syncthreads();
  #pragma unroll
  for (int p = 0; p < 2; p++) {
    int lin = tid + 256 * p;
    int d = lin & 63, tc = (lin >> 6) * 8;
    ushort_t tmp[8];
    #pragma unroll
    for (int u = 0; u < 8; u++) tmp[u] = L[tc + u][d];
    *(uint4*)(dst + (size_t)(bh * HD + d) * S_LEN + t0 + tc) = *(uint4*)tmp;
  }
}

// ---------------- bf16 MFMA GEMM (unchanged from R5): C[2048,1024] = A*B^T ----------------
template <int MODE, int NSEG>
__global__ __launch_bounds__(256) void gemm_mf(
    const ushort_t* __restrict__ A0, const ushort_t* __restrict__ A1, const ushort_t* __restrict__ A2,
    const ushort_t* __restrict__ B0, const ushort_t* __restrict__ B1, const ushort_t* __restrict__ B2,
    float* __restrict__ Cf, const float* __restrict__ T,
    ushort_t* __restrict__ Cb0, ushort_t* __restrict__ Cb1, ushort_t* __restrict__ Cb2,
    float alpha) {
  const int K = 1024;
  __shared__ __bf16 As[64][40];
  __shared__ __bf16 Bs[128][40];
  int tid = threadIdx.x;
  int m0 = blockIdx.y * 64, n0 = blockIdx.x * 128;

  const ushort_t* Bsel = B0;
  ushort_t* Cbz = Cb0;
  if (MODE == 0) {
    int z = blockIdx.z;
    Bsel = (z == 0) ? B0 : (z == 1) ? B1 : B2;
    Cbz = (z == 0) ? Cb0 : (z == 1) ? Cb1 : Cb2;
  }

  int lane = tid & 63, wave = tid >> 6;
  int wrow = wave >> 1, wcol = wave & 1;
  int fr = lane & 15, q = lane >> 4;

  f32x4 acc[2][4] = {};

  int ar = tid >> 2, ac = (tid & 3) * 8;
  #pragma unroll 1
  for (int seg = 0; seg < NSEG; seg++) {
    const ushort_t* Aseg = (seg == 0) ? A0 : (seg == 1) ? A1 : A2;
    const ushort_t* Bseg = (MODE == 0) ? Bsel : ((seg == 0) ? B0 : (seg == 1) ? B1 : B2);
    const ushort_t* Ag = Aseg + (size_t)(m0 + ar) * K + ac;
    const ushort_t* Bg0 = Bseg + (size_t)(n0 + ar) * K + ac;
    const ushort_t* Bg1 = Bseg + (size_t)(n0 + 64 + ar) * K + ac;
    for (int k0 = 0; k0 < K; k0 += 32) {
      uint4 av = *(const uint4*)(Ag + k0);
      uint4 bv0 = *(const uint4*)(Bg0 + k0);
      uint4 bv1 = *(const uint4*)(Bg1 + k0);
      __syncthreads();
      *(uint4*)&As[ar][ac] = av;
      *(uint4*)&Bs[ar][ac] = bv0;
      *(uint4*)&Bs[64 + ar][ac] = bv1;
      __syncthreads();
      bf16x8 a0 = *(const bf16x8*)&As[wrow * 32 + fr][q * 8];
      bf16x8 a1 = *(const bf16x8*)&As[wrow * 32 + 16 + fr][q * 8];
      bf16x8 b0 = *(const bf16x8*)&Bs[wcol * 64 + fr][q * 8];
      bf16x8 b1 = *(const bf16x8*)&Bs[wcol * 64 + 16 + fr][q * 8];
      bf16x8 b2 = *(const bf16x8*)&Bs[wcol * 64 + 32 + fr][q * 8];
      bf16x8 b3 = *(const bf16x8*)&Bs[wcol * 64 + 48 + fr][q * 8];
      acc[0][0] = __builtin_amdgcn_mfma_f32_16x16x32_bf16(a0, b0, acc[0][0], 0, 0, 0);
      acc[0][1] = __builtin_amdgcn_mfma_f32_16x16x32_bf16(a0, b1, acc[0][1], 0, 0, 0);
      acc[0][2] = __builtin_amdgcn_mfma_f32_16x16x32_bf16(a0, b2, acc[0][2], 0, 0, 0);
      acc[0][3] = __builtin_amdgcn_mfma_f32_16x16x32_bf16(a0, b3, acc[0][3], 0, 0, 0);
      acc[1][0] = __builtin_amdgcn_mfma_f32_16x16x32_bf16(a1, b0, acc[1][0], 0, 0, 0);
      acc[1][1] = __builtin_amdgcn_mfma_f32_16x16x32_bf16(a1, b1, acc[1][1], 0, 0, 0);
      acc[1][2] = __builtin_amdgcn_mfma_f32_16x16x32_bf16(a1, b2, acc[1][2], 0, 0, 0);
      acc[1][3] = __builtin_amdgcn_mfma_f32_16x16x32_bf16(a1, b3, acc[1][3], 0, 0, 0);
    }
  }

  #pragma unroll
  for (int mi = 0; mi < 2; mi++)
    #pragma unroll
    for (int ni = 0; ni < 4; ni++) {
      int col = n0 + wcol * 64 + ni * 16 + fr;
      int row0 = m0 + wrow * 32 + mi * 16 + q * 4;
      #pragma unroll
      for (int r = 0; r < 4; r++) {
        size_t idx = (size_t)(row0 + r) * E_DIM + col;
        float v = acc[mi][ni][r];
        if (MODE == 0) {
          Cbz[idx] = f2bu(v);
        } else if (MODE == 1) {
          Cb0[idx] = f2bu(T[idx] - v);
        } else {
          float nv = Cf[idx] + alpha * v;
          Cf[idx] = nv;
          Cb0[idx] = f2bu(nv);
        }
      }
    }
}

// ====================== MFMA attention, LDS-staged ======================
// MFMA 16x16x32: A[m=lane&15][k=q*8+u], B[n=lane&15][k=q*8+u], C: col=lane&15, row=q*4+reg.
// Each block: i-tile (or j-tile) of 64 rows, 4 waves = 4 bands of 16 rows.
// Inner tiles staged cooperatively in LDS (pad to 72: row=144B, 2-way banks on b128 reads).

// ---- fused fwd: single-pass flash with online softmax; emits m, 1/l, g=O-Xs (bf16), Dv ----
__global__ __launch_bounds__(256) void fwd_fused(const ushort_t* __restrict__ Qg,
                                                 const ushort_t* __restrict__ Kg,
                                                 const ushort_t* __restrict__ Vt,
                                                 const float* __restrict__ Xs,
                                                 float* __restrict__ mbuf,
                                                 float* __restrict__ lbuf,
                                                 ushort_t* __restrict__ Gb,
                                                 float* __restrict__ Dv) {
  int it = 15 - blockIdx.x;
  int bh = blockIdx.y, b = bh >> 4, h = bh & 15;
  int tid = threadIdx.x, lane = tid & 63, wv = tid >> 6;
  int fr = lane & 15, q = lane >> 4;
  int i0 = it * 64, band = wv * 16;
  __shared__ ushort_t Kts[64][72];  // [j][d]
  __shared__ ushort_t Vts[64][72];  // [d][j]
  __shared__ ushort_t Ps[64][72];   // [i][j] (wave-private bands)

  const ushort_t* Qrow = Qg + (size_t)(b * S_LEN + i0 + band + fr) * E_DIM + h * HD;
  bf16x8 aq0 = ldg8(Qrow + q * 8);
  bf16x8 aq1 = ldg8(Qrow + 32 + q * 8);

  float m[4], l[4];
  #pragma unroll
  for (int r = 0; r < 4; r++) { m[r] = -1e30f; l[r] = 0.f; }
  f32x4 oacc[4] = {};

  for (int jt = 0; jt <= it; jt++) {
    int j0 = jt * 64;
    __syncthreads();
    #pragma unroll
    for (int t = 0; t < 2; t++) {
      int u = tid + 256 * t;
      int r = u >> 3, c8 = (u & 7) * 8;
      *(uint4*)&Kts[r][c8] = *(const uint4*)(Kg + (size_t)(b * S_LEN + j0 + r) * E_DIM + h * HD + c8);
      *(uint4*)&Vts[r][c8] = *(const uint4*)(Vt + (size_t)(bh * HD + r) * S_LEN + j0 + c8);
    }
    __syncthreads();
    f32x4 sA[4];
    #pragma unroll
    for (int nc = 0; nc < 4; nc++) {
      bf16x8 bk0 = *(const bf16x8*)&Kts[nc * 16 + fr][q * 8];
      bf16x8 bk1 = *(const bf16x8*)&Kts[nc * 16 + fr][32 + q * 8];
      f32x4 z = {};
      z = __builtin_amdgcn_mfma_f32_16x16x32_bf16(aq0, bk0, z, 0, 0, 0);
      sA[nc] = __builtin_amdgcn_mfma_f32_16x16x32_bf16(aq1, bk1, z, 0, 0, 0);
    }
    // mask + scale
    float sv[4][4];
    #pragma unroll
    for (int nc = 0; nc < 4; nc++)
      #pragma unroll
      for (int r = 0; r < 4; r++) {
        int row = i0 + band + q * 4 + r;
        int col = j0 + nc * 16 + fr;
        sv[nc][r] = (col <= row) ? sA[nc][r] * SC_C : -1e30f;
      }
    // online update per row r (rows owned by 16-lane fr-groups)
    #pragma unroll
    for (int r = 0; r < 4; r++) {
      float mx = fmaxf(fmaxf(sv[0][r], sv[1][r]), fmaxf(sv[2][r], sv[3][r]));
      #pragma unroll
      for (int off = 1; off < 16; off <<= 1) mx = fmaxf(mx, __shfl_xor(mx, off, 64));
      float mn = fmaxf(m[r], mx);
      float alpha = __expf(m[r] - mn);
      float ps = 0.f;
      #pragma unroll
      for (int nc = 0; nc < 4; nc++) {
        float p = __expf(sv[nc][r] - mn);  // masked: exp(-huge)=0
        Ps[band + q * 4 + r][nc * 16 + fr] = f2bu(p);
        ps += p;
      }
      #pragma unroll
      for (int off = 1; off < 16; off <<= 1) ps += __shfl_xor(ps, off, 64);
      l[r] = l[r] * alpha + ps;
      m[r] = mn;
      #pragma unroll
      for (int nc = 0; nc < 4; nc++) oacc[nc][r] *= alpha;
    }
    // O += P V  (wave-private Ps rows)
    bf16x8 ap0 = *(const bf16x8*)&Ps[band + fr][q * 8];
    bf16x8 ap1 = *(const bf16x8*)&Ps[band + fr][32 + q * 8];
    #pragma unroll
    for (int nc = 0; nc < 4; nc++) {
      bf16x8 bv0 = *(const bf16x8*)&Vts[nc * 16 + fr][q * 8];
      bf16x8 bv1 = *(const bf16x8*)&Vts[nc * 16 + fr][32 + q * 8];
      oacc[nc] = __builtin_amdgcn_mfma_f32_16x16x32_bf16(ap0, bv0, oacc[nc], 0, 0, 0);
      oacc[nc] = __builtin_amdgcn_mfma_f32_16x16x32_bf16(ap1, bv1, oacc[nc], 0, 0, 0);
    }
  }
  // epilogue
  float linv[4];
  #pragma unroll
  for (int r = 0; r < 4; r++) linv[r] = 1.0f / l[r];
  float dpart[4] = {};
  #pragma unroll
  for (int nc = 0; nc < 4; nc++)
    #pragma unroll
    for (int r = 0; r < 4; r++) {
      int row = i0 + band + q * 4 + r;
      size_t gi = (size_t)(b * S_LEN + row) * E_DIM + h * HD + nc * 16 + fr;
      float o = oacc[nc][r] * linv[r];
      float g = o - Xs[gi];
      Gb[gi] = f2bu(g);
      dpart[r] += g * o;
    }
  #pragma unroll
  for (int r = 0; r < 4; r++) {
    #pragma unroll
    for (int off = 1; off < 16; off <<= 1) dpart[r] += __shfl_xor(dpart[r], off, 64);
  }
  if (fr == 0) {
    #pragma unroll
    for (int r = 0; r < 4; r++) {
      size_t sid = (size_t)bh * S_LEN + i0 + band + q * 4 + r;
      mbuf[sid] = m[r];
      lbuf[sid] = linv[r];
      Dv[sid] = dpart[r];
    }
  }
}

// ---- bwd dq: S=QK^T, dP=GV^T, dS->LDS, dq = dS*K^T (Kt tile) ----
__global__ __launch_bounds__(256) void bwd_q(const ushort_t* __restrict__ Qg,
                                             const ushort_t* __restrict__ Kg,
                                             const ushort_t* __restrict__ Vg,
                                             const ushort_t* __restrict__ Gg,
                                             const ushort_t* __restrict__ Kt,
                                             const float* __restrict__ mbuf,
                                             const float* __restrict__ lbuf,
                                             const float* __restrict__ Dv,
                                             ushort_t* __restrict__ GQ) {
  int it = 15 - blockIdx.x;
  int bh = blockIdx.y, b = bh >> 4, h = bh & 15;
  int tid = threadIdx.x, lane = tid & 63, wv = tid >> 6;
  int fr = lane & 15, q = lane >> 4;
  int i0 = it * 64, band = wv * 16;
  __shared__ ushort_t Kts[64][72];   // [j][d]
  __shared__ ushort_t Vts[64][72];   // [j][d]
  __shared__ ushort_t Ktt[64][72];   // [d][j]
  __shared__ ushort_t dSs[64][72];

  const ushort_t* Qrow = Qg + (size_t)(b * S_LEN + i0 + band + fr) * E_DIM + h * HD;
  const ushort_t* Grow = Gg + (size_t)(b * S_LEN + i0 + band + fr) * E_DIM + h * HD;
  bf16x8 aq0 = ldg8(Qrow + q * 8), aq1 = ldg8(Qrow + 32 + q * 8);
  bf16x8 ag0 = ldg8(Grow + q * 8), ag1 = ldg8(Grow + 32 + q * 8);

  float mrow[4], linv[4], Dr[4];
  #pragma unroll
  for (int r = 0; r < 4; r++) {
    size_t sid = (size_t)bh * S_LEN + i0 + band + q * 4 + r;
    mrow[r] = mbuf[sid]; linv[r] = lbuf[sid]; Dr[r] = Dv[sid];
  }
  f32x4 dqacc[4] = {};

  for (int jt = 0; jt <= it; jt++) {
    int j0 = jt * 64;
    __syncthreads();
    #pragma unroll
    for (int t = 0; t < 2; t++) {
      int u = tid + 256 * t;
      int r = u >> 3, c8 = (u & 7) * 8;
      *(uint4*)&Kts[r][c8] = *(const uint4*)(Kg + (size_t)(b * S_LEN + j0 + r) * E_DIM + h * HD + c8);
      *(uint4*)&Vts[r][c8] = *(const uint4*)(Vg + (size_t)(b * S_LEN + j0 + r) * E_DIM + h * HD + c8);
      *(uint4*)&Ktt[r][c8] = *(const uint4*)(Kt + (size_t)(bh * HD + r) * S_LEN + j0 + c8);
    }
    __syncthreads();
    f32x4 sA[4], dpA[4];
    #pragma unroll
    for (int nc = 0; nc < 4; nc++) {
      bf16x8 bk0 = *(const bf16x8*)&Kts[nc * 16 + fr][q * 8];
      bf16x8 bk1 = *(const bf16x8*)&Kts[nc * 16 + fr][32 + q * 8];
      bf16x8 bv0 = *(const bf16x8*)&Vts[nc * 16 + fr][q * 8];
      bf16x8 bv1 = *(const bf16x8*)&Vts[nc * 16 + fr][32 + q * 8];
      f32x4 z = {};
      z = __builtin_amdgcn_mfma_f32_16x16x32_bf16(aq0, bk0, z, 0, 0, 0);
      sA[nc] = __builtin_amdgcn_mfma_f32_16x16x32_bf16(aq1, bk1, z, 0, 0, 0);
      f32x4 z2 = {};
      z2 = __builtin_amdgcn_mfma_f32_16x16x32_bf16(ag0, bv0, z2, 0, 0, 0);
      dpA[nc] = __builtin_amdgcn_mfma_f32_16x16x32_bf16(ag1, bv1, z2, 0, 0, 0);
    }
    #pragma unroll
    for (int nc = 0; nc < 4; nc++)
      #pragma unroll
      for (int r = 0; r < 4; r++) {
        int row = i0 + band + q * 4 + r;
        int col = j0 + nc * 16 + fr;
        float ds = 0.f;
        if (col <= row) {
          float P = __expf(sA[nc][r] * SC_C - mrow[r]) * linv[r];
          ds = P * (dpA[nc][r] - Dr[r]) * SC_C;
        }
        dSs[band + q * 4 + r][nc * 16 + fr] = f2bu(ds);  // wave-private
      }
    bf16x8 ad0 = *(const bf16x8*)&dSs[band + fr][q * 8];
    bf16x8 ad1 = *(const bf16x8*)&dSs[band + fr][32 + q * 8];
    #pragma unroll
    for (int nc = 0; nc < 4; nc++) {
      bf16x8 bt0 = *(const bf16x8*)&Ktt[nc * 16 + fr][q * 8];
      bf16x8 bt1 = *(const bf16x8*)&Ktt[nc * 16 + fr][32 + q * 8];
      dqacc[nc] = __builtin_amdgcn_mfma_f32_16x16x32_bf16(ad0, bt0, dqacc[nc], 0, 0, 0);
      dqacc[nc] = __builtin_amdgcn_mfma_f32_16x16x32_bf16(ad1, bt1, dqacc[nc], 0, 0, 0);
    }
  }
  #pragma unroll
  for (int nc = 0; nc < 4; nc++)
    #pragma unroll
    for (int r = 0; r < 4; r++) {
      int row = i0 + band + q * 4 + r;
      size_t gi = (size_t)(b * S_LEN + row) * E_DIM + h * HD + nc * 16 + fr;
      GQ[gi] = f2bu(dqacc[nc][r]);
    }
}

// ---- bwd dk/dv: ST=K*Q^T, dPT=V*G^T; PT/dST->LDS; dv=PT*G^T(Gt), dk=dST*Q^T(Qt) ----
__global__ __launch_bounds__(256) void bwd_kv(const ushort_t* __restrict__ Qg,
                                              const ushort_t* __restrict__ Kg,
                                              const ushort_t* __restrict__ Vg,
                                              const ushort_t* __restrict__ Gg,
                                              const ushort_t* __restrict__ Qt,
                                              const ushort_t* __restrict__ Gt,
                                              const float* __restrict__ mbuf,
                                              const float* __restrict__ lbuf,
                                              const float* __restrict__ Dv,
                                              ushort_t* __restrict__ GK,
                                              ushort_t* __restrict__ GV) {
  int jt = blockIdx.x;  // jt=0 heaviest, dispatched first
  int bh = blockIdx.y, b = bh >> 4, h = bh & 15;
  int tid = threadIdx.x, lane = tid & 63, wv = tid >> 6;
  int fr = lane & 15, q = lane >> 4;
  int j0 = jt * 64, band = wv * 16;
  __shared__ ushort_t Qs_[64][72];  // [i][d]
  __shared__ ushort_t Gs_[64][72];  // [i][d]
  __shared__ ushort_t Qtt[64][72];  // [d][i]
  __shared__ ushort_t Gtt[64][72];  // [d][i]
  __shared__ ushort_t PT[64][72];   // [j][i]
  __shared__ ushort_t dST[64][72];  // [j][i]

  const ushort_t* Krow = Kg + (size_t)(b * S_LEN + j0 + band + fr) * E_DIM + h * HD;
  const ushort_t* Vrow = Vg + (size_t)(b * S_LEN + j0 + band + fr) * E_DIM + h * HD;
  bf16x8 ak0 = ldg8(Krow + q * 8), ak1 = ldg8(Krow + 32 + q * 8);
  bf16x8 av0 = ldg8(Vrow + q * 8), av1 = ldg8(Vrow + 32 + q * 8);

  f32x4 dkacc[4] = {}, dvacc[4] = {};

  for (int i_t = jt; i_t < 16; i_t++) {
    int i0 = i_t * 64;
    __syncthreads();
    #pragma unroll
    for (int t = 0; t < 2; t++) {
      int u = tid + 256 * t;
      int r = u >> 3, c8 = (u & 7) * 8;
      *(uint4*)&Qs_[r][c8] = *(const uint4*)(Qg + (size_t)(b * S_LEN + i0 + r) * E_DIM + h * HD + c8);
      *(uint4*)&Gs_[r][c8] = *(const uint4*)(Gg + (size_t)(b * S_LEN + i0 + r) * E_DIM + h * HD + c8);
      *(uint4*)&Qtt[r][c8] = *(const uint4*)(Qt + (size_t)(bh * HD + r) * S_LEN + i0 + c8);
      *(uint4*)&Gtt[r][c8] = *(const uint4*)(Gt + (size_t)(bh * HD + r) * S_LEN + i0 + c8);
    }
    __syncthreads();
    float mc[4], lc[4], Dc[4];
    #pragma unroll
    for (int nc = 0; nc < 4; nc++) {
      size_t sid = (size_t)bh * S_LEN + i0 + nc * 16 + fr;
      mc[nc] = mbuf[sid]; lc[nc] = lbuf[sid]; Dc[nc] = Dv[sid];
    }
    f32x4 stA[4], dptA[4];
    #pragma unroll
    for (int nc = 0; nc < 4; nc++) {
      bf16x8 bq0 = *(const bf16x8*)&Qs_[nc * 16 + fr][q * 8];
      bf16x8 bq1 = *(const bf16x8*)&Qs_[nc * 16 + fr][32 + q * 8];
      bf16x8 bg0 = *(const bf16x8*)&Gs_[nc * 16 + fr][q * 8];
      bf16x8 bg1 = *(const bf16x8*)&Gs_[nc * 16 + fr][32 + q * 8];
      f32x4 z = {};
      z = __builtin_amdgcn_mfma_f32_16x16x32_bf16(ak0, bq0, z, 0, 0, 0);
      stA[nc] = __builtin_amdgcn_mfma_f32_16x16x32_bf16(ak1, bq1, z, 0, 0, 0);
      f32x4 z2 = {};
      z2 = __builtin_amdgcn_mfma_f32_16x16x32_bf16(av0, bg0, z2, 0, 0, 0);
      dptA[nc] = __builtin_amdgcn_mfma_f32_16x16x32_bf16(av1, bg1, z2, 0, 0, 0);
    }
    #pragma unroll
    for (int nc = 0; nc < 4; nc++)
      #pragma unroll
      for (int r = 0; r < 4; r++) {
        int jrow = j0 + band + q * 4 + r;
        int icol = i0 + nc * 16 + fr;
        float P = 0.f, ds = 0.f;
        if (icol >= jrow) {
          P = __expf(stA[nc][r] * SC_C - mc[nc]) * lc[nc];
          ds = P * (dptA[nc][r] - Dc[nc]) * SC_C;
        }
        PT[band + q * 4 + r][nc * 16 + fr] = f2bu(P);   // wave-private
        dST[band + q * 4 + r][nc * 16 + fr] = f2bu(ds);
      }
    bf16x8 ap0 = *(const bf16x8*)&PT[band + fr][q * 8];
    bf16x8 ap1 = *(const bf16x8*)&PT[band + fr][32 + q * 8];
    bf16x8 ad0 = *(const bf16x8*)&dST[band + fr][q * 8];
    bf16x8 ad1 = *(const bf16x8*)&dST[band + fr][32 + q * 8];
    #pragma unroll
    for (int nc = 0; nc < 4; nc++) {
      bf16x8 bg0 = *(const bf16x8*)&Gtt[nc * 16 + fr][q * 8];
      bf16x8 bg1 = *(const bf16x8*)&Gtt[nc * 16 + fr][32 + q * 8];
      bf16x8 bq0 = *(const bf16x8*)&Qtt[nc * 16 + fr][q * 8];
      bf16x8 bq1 = *(const bf16x8*)&Qtt[nc * 16 + fr][32 + q * 8];
      dvacc[nc] = __builtin_amdgcn_mfma_f32_16x16x32_bf16(ap0, bg0, dvacc[nc], 0, 0, 0);
      dvacc[nc] = __builtin_amdgcn_mfma_f32_16x16x32_bf16(ap1, bg1, dvacc[nc], 0, 0, 0);
      dkacc[nc] = __builtin_amdgcn_mfma_f32_16x16x32_bf16(ad0, bq0, dkacc[nc], 0, 0, 0);
      dkacc[nc] = __builtin_amdgcn_mfma_f32_16x16x32_bf16(ad1, bq1, dkacc[nc], 0, 0, 0);
    }
  }
  #pragma unroll
  for (int nc = 0; nc < 4; nc++)
    #pragma unroll
    for (int r = 0; r < 4; r++) {
      int jrow = j0 + band + q * 4 + r;
      size_t gi = (size_t)(b * S_LEN + jrow) * E_DIM + h * HD + nc * 16 + fr;
      GK[gi] = f2bu(dkacc[nc][r]);
      GV[gi] = f2bu(dvacc[nc][r]);
    }
}

// ---------------- launch ----------------
extern "C" void kernel_launch(void* const* d_in, const int* in_sizes, int n_in,
                              void* d_out, int out_size, void* d_ws, size_t ws_size,
                              hipStream_t stream) {
  const float* T1 = (const float*)d_in[0];
  const float* Wq = (const float*)d_in[1];
  const float* Wk = (const float*)d_in[2];
  const float* Wv = (const float*)d_in[3];
  const float* Wo = (const float*)d_in[4];

  const size_t M2 = 2097152;   // 2048*1024
  const size_t M1 = 1048576;
  float* w = (float*)d_ws;
  float* Xs = w;                       // 8 MB fp32 target
  float* mS = Xs + M2;                 // 64K f32
  float* lS = mS + 65536;
  float* DvS = lS + 65536;
  ushort_t* u = (ushort_t*)(DvS + 65536);
  ushort_t* W0 = u;          ushort_t* W1 = W0 + M1;  ushort_t* W2 = W1 + M1;
  ushort_t* W3 = W2 + M1;    ushort_t* W4 = W3 + M1;  ushort_t* W5 = W4 + M1;
  ushort_t* Qb = W5 + M1;    ushort_t* Kb = Qb + M2;  ushort_t* Vb = Kb + M2;
  ushort_t* Qt = Vb + M2;    ushort_t* Kt = Qt + M2;  ushort_t* Vt = Kt + M2;
  ushort_t* Gt = Vt + M2;
  ushort_t* Gb = Gt + M2;
  ushort_t* GQb = Gb + M2;   ushort_t* GKb = GQb + M2; ushort_t* GVb = GKb + M2;
  ushort_t* X2b = GVb + M2;
  ushort_t* Rb = GQb;        // stage-1 aliases
  ushort_t* Xsb = GKb;
  float* X2 = (float*)d_out;

  hipMemsetAsync(Xs, 0, M2 * sizeof(float), stream);
  hipMemsetAsync(Xsb, 0, M2 * sizeof(ushort_t), stream);
  hipMemsetAsync(X2, 0, M2 * sizeof(float), stream);
  hipMemsetAsync(X2b, 0, M2 * sizeof(ushort_t), stream);

  dim3 pgrid(16, 16);
  dim3 ggrid(8, 32);
  dim3 ggrid3(8, 32, 3);
  dim3 agrid(16, BH_CNT);
  dim3 tgrid3(16, BH_CNT, 3);
  dim3 tgrid1(16, BH_CNT, 1);

  // ---- stage 1 ----
  prep_w<<<pgrid, 256, 0, stream>>>(Wo, W0, W1);
  for (int t = 0; t < 3; t++) {
    gemm_mf<1, 1><<<ggrid, 256, 0, stream>>>(Xsb, nullptr, nullptr, W0, nullptr, nullptr,
                                             nullptr, T1, Rb, nullptr, nullptr, 0.f);
    gemm_mf<2, 1><<<ggrid, 256, 0, stream>>>(Rb, nullptr, nullptr, W1, nullptr, nullptr,
                                             Xs, nullptr, Xsb, nullptr, nullptr, LR_C);
  }
  prep_w<<<pgrid, 256, 0, stream>>>(Wq, W0, W3);
  prep_w<<<pgrid, 256, 0, stream>>>(Wk, W1, W4);
  prep_w<<<pgrid, 256, 0, stream>>>(Wv, W2, W5);

  // ---- stage 2 ----
  for (int t = 0; t < 3; t++) {
    gemm_mf<0, 1><<<ggrid3, 256, 0, stream>>>(X2b, nullptr, nullptr, W0, W1, W2,
                                              nullptr, nullptr, Qb, Kb, Vb, 0.f);
    tr_head<<<tgrid3, 256, 0, stream>>>(Qb, Kb, Vb, Qt, Kt, Vt);
    fwd_fused<<<agrid, 256, 0, stream>>>(Qb, Kb, Vt, Xs, mS, lS, Gb, DvS);
    tr_head<<<tgrid1, 256, 0, stream>>>(Gb, nullptr, nullptr, Gt, nullptr, nullptr);
    bwd_q<<<agrid, 256, 0, stream>>>(Qb, Kb, Vb, Gb, Kt, mS, lS, DvS, GQb);
    bwd_kv<<<agrid, 256, 0, stream>>>(Qb, Kb, Vb, Gb, Qt, Gt, mS, lS, DvS, GKb, GVb);
    gemm_mf<2, 3><<<ggrid, 256, 0, stream>>>(GQb, GKb, GVb, W3, W4, W5,
                                             X2, nullptr, X2b, nullptr, nullptr, -LR_C);
  }
}